// Round 7
// baseline (713.763 us; speedup 1.0000x reference)
//
#include <hip/hip_runtime.h>
#include <hip/hip_bf16.h>

#define DEV static __device__ __forceinline__

typedef __attribute__((ext_vector_type(16))) float f32x16;
typedef __attribute__((ext_vector_type(8)))  short bf16x8;

DEV ushort f2bf(float f){
  union { float f; unsigned u; } v; v.f = f;
  return (ushort)((v.u + 0x7FFFu + ((v.u >> 16) & 1u)) >> 16);
}
DEV float bf2f(ushort u){
  union { unsigned u; float f; } v; v.u = ((unsigned)u) << 16;
  return v.f;
}

// async global->LDS, 16B per lane; LDS dest is wave-uniform base + lane*16.
DEV void gload16(const ushort* g, ushort* l) {
  __builtin_amdgcn_global_load_lds(
      (const __attribute__((address_space(1))) unsigned*)g,
      (__attribute__((address_space(3))) unsigned*)l, 16, 0, 0);
}

// ---------------------------------------------------------------------------
// Elementwise f32 -> bf16 (8 elems/thread, grid-stride).
// ---------------------------------------------------------------------------
__global__ __launch_bounds__(256)
void cvt_bf16(const float* __restrict__ src, ushort* __restrict__ dst, long n8)
{
  const long stride = (long)gridDim.x * 256;
  for (long i = (long)blockIdx.x * 256 + threadIdx.x; i < n8; i += stride) {
    const float4 a = *(const float4*)(src + i * 8);
    const float4 b = *(const float4*)(src + i * 8 + 4);
    union { ushort u[8]; uint4 v; } pk;
    pk.u[0] = f2bf(a.x); pk.u[1] = f2bf(a.y); pk.u[2] = f2bf(a.z); pk.u[3] = f2bf(a.w);
    pk.u[4] = f2bf(b.x); pk.u[5] = f2bf(b.y); pk.u[6] = f2bf(b.z); pk.u[7] = f2bf(b.w);
    *(uint4*)(dst + i * 8) = pk.v;
  }
}

// ---------------------------------------------------------------------------
// bf16 GEMM: C[M,N] = (A @ B^T)*scale, B is [N,K] K-contiguous.
// Tile 128x256, 8 waves (2x4 of 64x64 each) -> acc = 64 VGPR/wave; total
// ~115 regs -> __launch_bounds__(512,4) = 2 BLOCKS/CU (the round-6 kernel's
// 128-reg acc + 128KB LDS forced 1 block/CU lockstep; independent blocks
// cover each other's barrier stalls).  K in groups of 16; LDS = 4-slot ring
// (48 KB).  ONE s_barrier + one counted per-wave vmcnt per group (ring-4:
// the DMA target slot g+2 is never a slot being read, and slot reuse has >=2
// barriers between last read and next DMA write).  vmcnt never drains to 0
// mid-loop (T4).  [kb][row][8] subtiling: linear for DMA, conflict-free
// ds_read_b128 (0 conflicts measured r2-r6).
// Staging per group: B = 8 chunks (1/wave), A = 4 chunks (waves 0-3) ->
// waves 0-3 have 2 loads in flight per group (vmcnt(2)), waves 4-7 one
// (vmcnt(1)) — wave-uniform branch.
// Frag k-map (32x32x16, r6-verified): kb = lane>>5, row = base + (lane&31).
// C/D: col=lane&31, row=(reg&3)+8*(reg>>2)+4*(lane>>5)  (m74/m101).
// Requires M%128==0, N%256==0, K%64==0.
// ---------------------------------------------------------------------------
template<bool BY_FAST>
__global__ __launch_bounds__(512, 4)
void gemm_t(const ushort* __restrict__ A, const ushort* __restrict__ B,
            ushort* __restrict__ C, int K, int N, int nbx, int nby,
            long sA, long sB, long sC, float scale)
{
  __shared__ __align__(16) ushort As[4][2][128][8];  // 16 KB
  __shared__ __align__(16) ushort Bs[4][2][256][8];  // 32 KB

  const int tid = threadIdx.x, lane = tid & 63, wid = tid >> 6;
  const int wr = wid >> 2, wc = wid & 3;  // 2 x 4 waves of 64x64

  // bijective XCD-chunk swizzle (m204)
  const int nwg = gridDim.x;
  const int q = nwg >> 3, r = nwg & 7;
  const int xcd = blockIdx.x & 7, lid = blockIdx.x >> 3;
  const int id = (xcd < r ? xcd * (q + 1) : r * (q + 1) + (xcd - r) * q) + lid;
  const int per = nbx * nby;
  const int z = id / per, rem = id - z * per;
  const int bx = BY_FAST ? rem / nby : rem % nbx;
  const int by = BY_FAST ? rem % nby : rem / nbx;

  const int bm = by * 128, bn = bx * 256;
  const long Ab = (long)z * sA, Bb = (long)z * sB, Cb = (long)z * sC;

  f32x16 acc[2][2];
  #pragma unroll
  for (int i = 0; i < 2; i++)
    #pragma unroll
    for (int j = 0; j < 2; j++)
      #pragma unroll
      for (int e = 0; e < 16; e++)
        acc[i][j][e] = 0.f;

  // Staging: B slot = 8 KB = 8 chunks (kb=wid>>2, rq=wid&3); A slot = 4 KB =
  // 4 chunks (kb=wid>>1, rq=wid&1, waves 0-3 only). 1 KB per gload16.
  const int kbB = wid >> 2, rqB = wid & 3;
  const int kbA = wid >> 1, rqA = wid & 1;
  const ushort* bgp = B + Bb + (long)(bn + rqB * 64 + lane) * K + kbB * 8;
  const ushort* agp = A + Ab + (long)(bm + rqA * 64 + lane) * K + kbA * 8;

  auto STAGE = [&](int g, int rg) {
    gload16(bgp + g * 16, &Bs[rg][kbB][rqB * 64][0]);
    if (wid < 4) gload16(agp + g * 16, &As[rg][kbA][rqA * 64][0]);
  };

  const int NG = K >> 4;  // multiple of 4
  STAGE(0, 0); STAGE(1, 1);
  if (wid < 4) asm volatile("s_waitcnt vmcnt(2)" ::: "memory");
  else         asm volatile("s_waitcnt vmcnt(1)" ::: "memory");
  __builtin_amdgcn_s_barrier();
  asm volatile("" ::: "memory");

  const int lkb = lane >> 5, lr = lane & 31;

  auto GROUP = [&](int g, int rg, int rg2) {
    bf16x8 av[2], bv[2];
    av[0] = *(const bf16x8*)&As[rg][lkb][wr * 64 + lr][0];
    av[1] = *(const bf16x8*)&As[rg][lkb][wr * 64 + 32 + lr][0];
    bv[0] = *(const bf16x8*)&Bs[rg][lkb][wc * 64 + lr][0];
    bv[1] = *(const bf16x8*)&Bs[rg][lkb][wc * 64 + 32 + lr][0];
    if (g + 2 < NG) STAGE(g + 2, rg2);
    __builtin_amdgcn_s_setprio(1);
    acc[0][0] = __builtin_amdgcn_mfma_f32_32x32x16_bf16(av[0], bv[0], acc[0][0], 0, 0, 0);
    acc[0][1] = __builtin_amdgcn_mfma_f32_32x32x16_bf16(av[0], bv[1], acc[0][1], 0, 0, 0);
    acc[1][0] = __builtin_amdgcn_mfma_f32_32x32x16_bf16(av[1], bv[0], acc[1][0], 0, 0, 0);
    acc[1][1] = __builtin_amdgcn_mfma_f32_32x32x16_bf16(av[1], bv[1], acc[1][1], 0, 0, 0);
    __builtin_amdgcn_s_setprio(0);
    // boundary: this wave's stage(g+1) chunks landed; stage(g+2) stays in
    // flight. Barrier extends "landed" to all waves' chunks.
    if (g + 2 < NG) {
      if (wid < 4) asm volatile("s_waitcnt vmcnt(2)" ::: "memory");
      else         asm volatile("s_waitcnt vmcnt(1)" ::: "memory");
    } else if (g + 1 < NG) {
      asm volatile("s_waitcnt vmcnt(0)" ::: "memory");
    }
    __builtin_amdgcn_s_barrier();
    asm volatile("" ::: "memory");
  };

  for (int g = 0; g < NG; g += 4) {
    GROUP(g + 0, 0, 2);
    GROUP(g + 1, 1, 3);
    GROUP(g + 2, 2, 0);
    GROUP(g + 3, 3, 1);
  }

  // C/D 32x32: col=lane&31, row=(reg&3)+8*(reg>>2)+4*(lane>>5).
  #pragma unroll
  for (int mi = 0; mi < 2; mi++)
    #pragma unroll
    for (int ni = 0; ni < 2; ni++)
      #pragma unroll
      for (int rr = 0; rr < 16; rr++) {
        const int row = bm + wr * 64 + mi * 32 + (rr & 3) + 8 * (rr >> 2) + 4 * lkb;
        const int col = bn + wc * 64 + ni * 32 + lr;
        C[Cb + (long)row * N + col] = f2bf(acc[mi][ni][rr] * scale);
      }
}

// ---------------------------------------------------------------------------
// Softmax over c (2048) per (b,s) row of S (bf16); wsum[b,c] += softmax row.
// 512 blocks (16 x 32): wave owns 8 rows in regs; cross-wave LDS reduce;
// one atomicAdd per c per block.
// ---------------------------------------------------------------------------
__global__ __launch_bounds__(256)
void softmax_wsum(const ushort* __restrict__ S, float* __restrict__ wsum)
{
  const int b = blockIdx.x;
  const int s0 = blockIdx.y * 32;
  const int lane = threadIdx.x & 63;
  const int w = threadIdx.x >> 6;
  __shared__ float red[4][2048];
  const ushort* Sb = S + (((long)b * 1024) + s0 + w * 8) * 2048;

  float acc[32];
  #pragma unroll
  for (int i = 0; i < 32; i++) acc[i] = 0.f;

  for (int r = 0; r < 8; r++) {
    const ushort* row = Sb + (long)r * 2048;
    float v[32];
    #pragma unroll
    for (int i = 0; i < 4; i++) {
      uint4 u = *(const uint4*)(row + i * 512 + lane * 8);
      const ushort* up = (const ushort*)&u;
      #pragma unroll
      for (int j = 0; j < 8; j++) v[i * 8 + j] = bf2f(up[j]);
    }
    float m = v[0];
    #pragma unroll
    for (int i = 1; i < 32; i++) m = fmaxf(m, v[i]);
    #pragma unroll
    for (int o = 1; o < 64; o <<= 1) m = fmaxf(m, __shfl_xor(m, o));
    float ssum = 0.f;
    #pragma unroll
    for (int i = 0; i < 32; i++) { v[i] = __expf(v[i] - m); ssum += v[i]; }
    #pragma unroll
    for (int o = 1; o < 64; o <<= 1) ssum += __shfl_xor(ssum, o);
    const float inv = 1.f / ssum;
    #pragma unroll
    for (int i = 0; i < 32; i++) acc[i] += v[i] * inv;
  }

  #pragma unroll
  for (int i = 0; i < 4; i++)
    #pragma unroll
    for (int j = 0; j < 8; j++)
      red[w][i * 512 + lane * 8 + j] = acc[i * 8 + j];
  __syncthreads();

  float* wb = wsum + b * 2048;
  #pragma unroll
  for (int k = 0; k < 8; k++) {
    const int c = k * 256 + threadIdx.x;
    atomicAdd(&wb[c], red[0][c] + red[1][c] + red[2][c] + red[3][c]);
  }
}

// t[b,d] = sum_c wsum[b,c] * cyc16[b,c,d]. 320 threads, 4 d's each (uint4
// row segments, fully coalesced); 64-c chunks; 4 atomicAdds per thread.
__global__ __launch_bounds__(320)
void wcyc_kernel(const ushort* __restrict__ cyc, const float* __restrict__ wsum,
                 float* __restrict__ t)
{
  const int b = blockIdx.x;
  const int c0 = blockIdx.y * 64;
  const int d = threadIdx.x * 4;
  const ushort* cb = cyc + ((long)b * 2048 + c0) * 1280 + d;
  const float* wb = wsum + b * 2048 + c0;
  float4 a = {0.f, 0.f, 0.f, 0.f};
  for (int c = 0; c < 64; c++) {
    const ushort4 u = *(const ushort4*)(cb + (long)c * 1280);
    const float w = wb[c];
    a.x += w * bf2f(u.x); a.y += w * bf2f(u.y);
    a.z += w * bf2f(u.z); a.w += w * bf2f(u.w);
  }
  atomicAdd(&t[b * 1280 + d + 0], a.x);
  atomicAdd(&t[b * 1280 + d + 1], a.y);
  atomicAdd(&t[b * 1280 + d + 2], a.z);
  atomicAdd(&t[b * 1280 + d + 3], a.w);
}

// xcat[b, 1280+d] = mean_s sub16[b,s,d]
__global__ __launch_bounds__(256)
void submean_kernel(const ushort* __restrict__ sub, float* __restrict__ xcat)
{
  const int b = blockIdx.x;
  const int d = blockIdx.y * 256 + threadIdx.x;
  const int s0 = blockIdx.z * 256;
  const ushort* sb = sub + ((long)b * 1024 + s0) * 1280 + d;
  float a = 0.f;
  for (int s = 0; s < 256; s++) a += bf2f(sb[(long)s * 1280]);
  atomicAdd(&xcat[b * 2560 + 1280 + d], a * (1.f / 1024.f));
}

// xcat[b, dp] = (1/1024) * sum_d t[b,d] * Wv[d,dp]
__global__ __launch_bounds__(256)
void xv_kernel(const float* __restrict__ t, const float* __restrict__ Wv,
               float* __restrict__ xcat)
{
  const int b = blockIdx.y;
  const int dp = blockIdx.x * 256 + threadIdx.x;
  __shared__ float tl[1280];
  for (int i = threadIdx.x; i < 1280; i += 256) tl[i] = t[b * 1280 + i];
  __syncthreads();
  float a = 0.f;
  for (int d = 0; d < 1280; d++) a += tl[d] * Wv[(long)d * 1280 + dp];
  xcat[b * 2560 + dp] = a * (1.f / 1024.f);
}

// h1 = relu(xcat @ W1 + b1)
__global__ __launch_bounds__(256)
void mlp1_kernel(const float* __restrict__ xcat, const float* __restrict__ W1,
                 const float* __restrict__ b1, float* __restrict__ h1)
{
  const int b = blockIdx.y;
  const int j = blockIdx.x * 256 + threadIdx.x;
  __shared__ float xl[2560];
  for (int i = threadIdx.x; i < 2560; i += 256) xl[i] = xcat[b * 2560 + i];
  __syncthreads();
  float a = b1[j];
  for (int d = 0; d < 2560; d++) a += xl[d] * W1[(long)d * 512 + j];
  h1[b * 512 + j] = fmaxf(a, 0.f);
}

// h2 = relu(h1 @ W2 + b2); out = sigmoid(h2 @ W3 + b3)
__global__ __launch_bounds__(64)
void mlp23_kernel(const float* __restrict__ h1, const float* __restrict__ W2,
                  const float* __restrict__ b2, const float* __restrict__ W3,
                  const float* __restrict__ b3, float* __restrict__ out)
{
  const int b = blockIdx.x;
  const int j = threadIdx.x;  // 64 threads = 1 wave
  __shared__ float hl[512];
  for (int i = j; i < 512; i += 64) hl[i] = h1[b * 512 + i];
  __syncthreads();
  float a = b2[j];
  for (int d = 0; d < 512; d++) a += hl[d] * W2[d * 64 + j];
  a = fmaxf(a, 0.f);
  float p = a * W3[j];
  #pragma unroll
  for (int o = 1; o < 64; o <<= 1) p += __shfl_xor(p, o);
  if (j == 0) out[b] = 1.f / (1.f + __expf(-(p + b3[0])));
}

extern "C" void kernel_launch(void* const* d_in, const int* in_sizes, int n_in,
                              void* d_out, int out_size, void* d_ws, size_t ws_size,
                              hipStream_t stream)
{
  const float* cyclase   = (const float*)d_in[0];
  const float* substrate = (const float*)d_in[1];
  // d_in[2], d_in[3]: masks — reference's masking is a no-op (replicated bug).
  const float* Wq = (const float*)d_in[4];
  const float* Wk = (const float*)d_in[5];
  const float* Wv = (const float*)d_in[6];
  const float* W1 = (const float*)d_in[7];
  const float* b1 = (const float*)d_in[8];
  const float* W2 = (const float*)d_in[9];
  const float* b2 = (const float*)d_in[10];
  const float* W3 = (const float*)d_in[11];
  const float* b3 = (const float*)d_in[12];
  float* out = (float*)d_out;
  (void)in_sizes; (void)n_in; (void)out_size; (void)ws_size;

  // Workspace (lifetime-aliased, ~193.5 MB):
  //   [0, 84M)            cyc16                     (cvt .. wcyc)
  //   [84M, 151.2M)       sub16(42M)+Mkq(3.3M)   -> S(67.1M) after both dead
  //   [151.2M, 193.1M)    Wq16+Wk16(6.6M)        -> T1(42M) after Mkq-gemm
  //   [193.1M, ...)       wsum/tbuf/xcat/h1
  char* ws = (char*)d_ws;
  ushort* cyc16 = (ushort*)ws;
  char*   base2 = ws + 83886080;
  ushort* sub16 = (ushort*)base2;
  ushort* Mkq   = (ushort*)(base2 + 41943040);
  ushort* S     = (ushort*)base2;
  char*   base3 = base2 + 67108864;
  ushort* T1    = (ushort*)base3;
  ushort* Wq16  = (ushort*)base3;
  ushort* Wk16  = (ushort*)(base3 + 3276800);
  char*   base4 = base3 + 41943040;
  float* wsum = (float*)base4;
  float* tbuf = (float*)(base4 + 131072);
  float* xcat = (float*)(base4 + 131072 + 81920);
  float* h1   = (float*)(base4 + 131072 + 81920 + 163840);

  hipMemsetAsync(wsum, 0, 16 * 2048 * 4, stream);
  hipMemsetAsync(tbuf, 0, 16 * 1280 * 4, stream);
  hipMemsetAsync(xcat, 0, 16 * 2560 * 4, stream);

  cvt_bf16<<<200, 256, 0, stream>>>(Wq, Wq16, 1280l * 1280 / 8);
  cvt_bf16<<<200, 256, 0, stream>>>(Wk, Wk16, 1280l * 1280 / 8);
  cvt_bf16<<<2048, 256, 0, stream>>>(substrate, sub16, 16l * 1024 * 1280 / 8);
  cvt_bf16<<<2048, 256, 0, stream>>>(cyclase, cyc16, 16l * 2048 * 1280 / 8);

  // Mkq = Wk @ Wq^T * (1/sqrt(1280))  [1280,1280]  (10 x 5 = 50 blocks)
  gemm_t<false><<<50, 512, 0, stream>>>(Wk16, Wq16, Mkq,
      1280, 1280, 5, 10, 0, 0, 0, 0.02795084971874737f);

  submean_kernel<<<dim3(16, 5, 4), 256, 0, stream>>>(sub16, xcat);

  // T1 = sub16 @ Mkq^T  [16384,1280]  (128 x 5 = 640 blocks, bx-fast:
  // A-panel hot, Mkq fully L2-resident per XCD)
  gemm_t<false><<<640, 512, 0, stream>>>(sub16, Mkq, T1,
      1280, 1280, 5, 128, 0, 0, 0, 1.0f);

  // S[b] = T1[b] @ cyc16[b]^T  [16,1024,2048]  (16 x 8 x 8 = 1024 blocks,
  // by-fast: cyc16 B-panel reused across 8 consecutive blocks)
  gemm_t<true><<<1024, 512, 0, stream>>>(T1, cyc16, S,
      1280, 2048, 8, 8, 1024l * 1280, 2048l * 1280, 1024l * 2048, 1.0f);

  softmax_wsum<<<dim3(16, 32), 256, 0, stream>>>(S, wsum);
  wcyc_kernel<<<dim3(16, 32), 320, 0, stream>>>(cyc16, wsum, tbuf);
  xv_kernel<<<dim3(5, 16), 256, 0, stream>>>(tbuf, Wv, xcat);
  mlp1_kernel<<<dim3(2, 16), 256, 0, stream>>>(xcat, W1, b1, h1);
  mlp23_kernel<<<16, 64, 0, stream>>>(h1, W2, b2, W3, b3, out);
}

// Round 8
// 679.397 us; speedup vs baseline: 1.0506x; 1.0506x over previous
//
#include <hip/hip_runtime.h>
#include <hip/hip_bf16.h>

#define DEV static __device__ __forceinline__

typedef __attribute__((ext_vector_type(16))) float f32x16;
typedef __attribute__((ext_vector_type(8)))  short bf16x8;

DEV ushort f2bf(float f){
  union { float f; unsigned u; } v; v.f = f;
  return (ushort)((v.u + 0x7FFFu + ((v.u >> 16) & 1u)) >> 16);
}
DEV float bf2f(ushort u){
  union { unsigned u; float f; } v; v.u = ((unsigned)u) << 16;
  return v.f;
}

// async global->LDS, 16B per lane; LDS dest is wave-uniform base + lane*16.
DEV void gload16(const ushort* g, ushort* l) {
  __builtin_amdgcn_global_load_lds(
      (const __attribute__((address_space(1))) unsigned*)g,
      (__attribute__((address_space(3))) unsigned*)l, 16, 0, 0);
}

// ---------------------------------------------------------------------------
// Elementwise f32 -> bf16 (8 elems/thread, grid-stride).
// ---------------------------------------------------------------------------
__global__ __launch_bounds__(256)
void cvt_bf16(const float* __restrict__ src, ushort* __restrict__ dst, long n8)
{
  const long stride = (long)gridDim.x * 256;
  for (long i = (long)blockIdx.x * 256 + threadIdx.x; i < n8; i += stride) {
    const float4 a = *(const float4*)(src + i * 8);
    const float4 b = *(const float4*)(src + i * 8 + 4);
    union { ushort u[8]; uint4 v; } pk;
    pk.u[0] = f2bf(a.x); pk.u[1] = f2bf(a.y); pk.u[2] = f2bf(a.z); pk.u[3] = f2bf(a.w);
    pk.u[4] = f2bf(b.x); pk.u[5] = f2bf(b.y); pk.u[6] = f2bf(b.z); pk.u[7] = f2bf(b.w);
    *(uint4*)(dst + i * 8) = pk.v;
  }
}

// ---------------------------------------------------------------------------
// bf16 GEMM, prefetch-depth-3 ring: C[M,N] = (A @ B^T)*scale, B [N,K]
// K-contiguous. Tile 256 x BN (BN=256 or 128), 8 waves (2x4), wave tile
// 128 x BN/4, MFMA 32x32x16. K in groups of 32; LDS = 4-slot ring filled by
// global_load_lds.
//
// WHY depth 3 (round-7 diagnosis): group cost tracked staged-bytes at
// ~7-10 B/cyc/CU across r2-r7 = in-flight bytes / DMA latency (Little's
// law; latency ~3-4k cyc under load). Depth 2 kept only ~4 KB/wave in
// flight. Depth 3 (ring-4 max: STAGE(g+3) hits slot (g-1)&3, readers done
// at end-of-(g-1) barrier) doubles it: boundary waits vmcnt(2*LG), i.e.
// groups g+2 AND g+3 stay in flight; never drains mid-loop (T4).
// One s_barrier per group; ds_reads are visible C++ loads so the compiler
// inserts fine-grained lgkmcnt before each MFMA (m97/m141 lesson).
// [kb][row][8] subtiling: linear for DMA, 0 bank conflicts (r2-r7 counters).
// Frag map (r6-verified): kb = kf*2 + (lane>>5), row = base + (lane&31).
// C/D 32x32 (m74/m101): col=lane&31, row=(reg&3)+8*(reg>>2)+4*(lane>>5).
// Requires M%256==0, N%BN==0, K%128==0.
// ---------------------------------------------------------------------------
template<int BN, bool BY_FAST>
__global__ __launch_bounds__(512, 2)
void gemm_d3(const ushort* __restrict__ A, const ushort* __restrict__ B,
             ushort* __restrict__ C, int K, int N, int nbx, int nby,
             long sA, long sB, long sC, float scale)
{
  constexpr int NT2 = BN / 128;   // n-tiles per wave (2 or 1)
  __shared__ __align__(16) ushort As[4][4][256][8];  // 64 KB
  __shared__ __align__(16) ushort Bs[4][4][BN][8];   // 64 or 32 KB

  const int tid = threadIdx.x, lane = tid & 63, wid = tid >> 6;
  const int wr = wid >> 2, wc = wid & 3;  // 2 x 4 waves

  // bijective XCD-chunk swizzle (m204)
  const int nwg = gridDim.x;
  const int q = nwg >> 3, r = nwg & 7;
  const int xcd = blockIdx.x & 7, lid = blockIdx.x >> 3;
  const int id = (xcd < r ? xcd * (q + 1) : r * (q + 1) + (xcd - r) * q) + lid;
  const int per = nbx * nby;
  const int z = id / per, rem = id - z * per;
  const int bx = BY_FAST ? rem / nby : rem % nbx;
  const int by = BY_FAST ? rem % nby : rem / nbx;

  const int bm = by * 256, bn = bx * BN;
  const long Ab = (long)z * sA, Bb = (long)z * sB, Cb = (long)z * sC;

  f32x16 acc[4][NT2];
  #pragma unroll
  for (int i = 0; i < 4; i++)
    #pragma unroll
    for (int j = 0; j < NT2; j++)
      #pragma unroll
      for (int e = 0; e < 16; e++)
        acc[i][j][e] = 0.f;

  // Staging. A: 16 chunks of 1KB/group, wave stages {2w, 2w+1} (kb=c>>2,
  // rq=c&3). B: BN=256 same as A; BN=128: 8 chunks, wave stages {w}
  // (kb=w>>1, rq=w&1). LG = loads/wave/group = 2 + NT2.
  const int cA0 = wid * 2, cA1 = wid * 2 + 1;
  const int kbA0 = cA0 >> 2, rqA0 = cA0 & 3;
  const int kbA1 = cA1 >> 2, rqA1 = cA1 & 3;
  const int kbB0 = (BN == 256) ? (cA0 >> 2) : (wid >> 1);
  const int rqB0 = (BN == 256) ? (cA0 & 3) : (wid & 1);
  const ushort* agp0 = A + Ab + (long)(bm + rqA0 * 64 + lane) * K + kbA0 * 8;
  const ushort* agp1 = A + Ab + (long)(bm + rqA1 * 64 + lane) * K + kbA1 * 8;
  const ushort* bgp0 = B + Bb + (long)(bn + rqB0 * 64 + lane) * K + kbB0 * 8;
  const ushort* bgp1 = B + Bb + (long)(bn + rqA1 * 64 + lane) * K + kbA1 * 8;

  auto STAGE = [&](int g, int rg) {
    gload16(agp0 + g * 32, &As[rg][kbA0][rqA0 * 64][0]);
    gload16(agp1 + g * 32, &As[rg][kbA1][rqA1 * 64][0]);
    gload16(bgp0 + g * 32, &Bs[rg][kbB0][rqB0 * 64][0]);
    if constexpr (BN == 256)
      gload16(bgp1 + g * 32, &Bs[rg][kbA1][rqA1 * 64][0]);
  };

  const int NG = K >> 5;  // multiple of 4
  STAGE(0, 0); STAGE(1, 1); STAGE(2, 2);
  // wait: group 0 landed (groups 1,2 = 2*LG loads still in flight)
  if constexpr (BN == 256) asm volatile("s_waitcnt vmcnt(8)" ::: "memory");
  else                     asm volatile("s_waitcnt vmcnt(6)" ::: "memory");
  __builtin_amdgcn_s_barrier();

  const int lkh = lane >> 5, lr = lane & 31;

  auto GROUP = [&](int g, int rg, int rg3) {
    if (g + 3 < NG) STAGE(g + 3, rg3);   // slot (g-1)&3: readers done @ end g-1
    bf16x8 av[4][2], bv[NT2][2];
    #pragma unroll
    for (int kf = 0; kf < 2; kf++) {
      #pragma unroll
      for (int mi = 0; mi < 4; mi++)
        av[mi][kf] = *(const bf16x8*)&As[rg][kf * 2 + lkh][wr * 128 + mi * 32 + lr][0];
      #pragma unroll
      for (int ni = 0; ni < NT2; ni++)
        bv[ni][kf] = *(const bf16x8*)&Bs[rg][kf * 2 + lkh][wc * (BN / 4) + ni * 32 + lr][0];
    }
    __builtin_amdgcn_s_setprio(1);
    #pragma unroll
    for (int kf = 0; kf < 2; kf++)
      #pragma unroll
      for (int mi = 0; mi < 4; mi++)
        #pragma unroll
        for (int ni = 0; ni < NT2; ni++)
          acc[mi][ni] = __builtin_amdgcn_mfma_f32_32x32x16_bf16(av[mi][kf], bv[ni][kf], acc[mi][ni], 0, 0, 0);
    __builtin_amdgcn_s_setprio(0);
    // boundary: my g+1 loads landed (g+2,g+3 stay in flight); barrier
    // extends to all waves. Tail ramps 2*LG -> LG -> 0.
    if (g + 3 < NG) {
      if constexpr (BN == 256) asm volatile("s_waitcnt vmcnt(8)" ::: "memory");
      else                     asm volatile("s_waitcnt vmcnt(6)" ::: "memory");
    } else if (g + 2 < NG) {
      if constexpr (BN == 256) asm volatile("s_waitcnt vmcnt(4)" ::: "memory");
      else                     asm volatile("s_waitcnt vmcnt(3)" ::: "memory");
    } else if (g + 1 < NG) {
      asm volatile("s_waitcnt vmcnt(0)" ::: "memory");
    }
    __builtin_amdgcn_s_barrier();
  };

  for (int g = 0; g < NG; g += 4) {
    GROUP(g + 0, 0, 3);
    GROUP(g + 1, 1, 0);
    GROUP(g + 2, 2, 1);
    GROUP(g + 3, 3, 2);
  }

  // C/D 32x32: col=lane&31, row=(reg&3)+8*(reg>>2)+4*(lane>>5).
  #pragma unroll
  for (int mi = 0; mi < 4; mi++)
    #pragma unroll
    for (int ni = 0; ni < NT2; ni++)
      #pragma unroll
      for (int rr = 0; rr < 16; rr++) {
        const int row = bm + wr * 128 + mi * 32 + (rr & 3) + 8 * (rr >> 2) + 4 * lkh;
        const int col = bn + wc * (BN / 4) + ni * 32 + lr;
        C[Cb + (long)row * N + col] = f2bf(acc[mi][ni][rr] * scale);
      }
}

// ---------------------------------------------------------------------------
// Softmax over c (2048) per (b,s) row of S (bf16); wsum[b,c] += softmax row.
// 512 blocks (16 x 32): wave owns 8 rows in regs; cross-wave LDS reduce;
// one atomicAdd per c per block.
// ---------------------------------------------------------------------------
__global__ __launch_bounds__(256)
void softmax_wsum(const ushort* __restrict__ S, float* __restrict__ wsum)
{
  const int b = blockIdx.x;
  const int s0 = blockIdx.y * 32;
  const int lane = threadIdx.x & 63;
  const int w = threadIdx.x >> 6;
  __shared__ float red[4][2048];
  const ushort* Sb = S + (((long)b * 1024) + s0 + w * 8) * 2048;

  float acc[32];
  #pragma unroll
  for (int i = 0; i < 32; i++) acc[i] = 0.f;

  for (int r = 0; r < 8; r++) {
    const ushort* row = Sb + (long)r * 2048;
    float v[32];
    #pragma unroll
    for (int i = 0; i < 4; i++) {
      uint4 u = *(const uint4*)(row + i * 512 + lane * 8);
      const ushort* up = (const ushort*)&u;
      #pragma unroll
      for (int j = 0; j < 8; j++) v[i * 8 + j] = bf2f(up[j]);
    }
    float m = v[0];
    #pragma unroll
    for (int i = 1; i < 32; i++) m = fmaxf(m, v[i]);
    #pragma unroll
    for (int o = 1; o < 64; o <<= 1) m = fmaxf(m, __shfl_xor(m, o));
    float ssum = 0.f;
    #pragma unroll
    for (int i = 0; i < 32; i++) { v[i] = __expf(v[i] - m); ssum += v[i]; }
    #pragma unroll
    for (int o = 1; o < 64; o <<= 1) ssum += __shfl_xor(ssum, o);
    const float inv = 1.f / ssum;
    #pragma unroll
    for (int i = 0; i < 32; i++) acc[i] += v[i] * inv;
  }

  #pragma unroll
  for (int i = 0; i < 4; i++)
    #pragma unroll
    for (int j = 0; j < 8; j++)
      red[w][i * 512 + lane * 8 + j] = acc[i * 8 + j];
  __syncthreads();

  float* wb = wsum + b * 2048;
  #pragma unroll
  for (int k = 0; k < 8; k++) {
    const int c = k * 256 + threadIdx.x;
    atomicAdd(&wb[c], red[0][c] + red[1][c] + red[2][c] + red[3][c]);
  }
}

// t[b,d] = sum_c wsum[b,c] * cyc16[b,c,d]. 320 threads, 4 d's each (uint4
// row segments, fully coalesced); 64-c chunks; 4 atomicAdds per thread.
__global__ __launch_bounds__(320)
void wcyc_kernel(const ushort* __restrict__ cyc, const float* __restrict__ wsum,
                 float* __restrict__ t)
{
  const int b = blockIdx.x;
  const int c0 = blockIdx.y * 64;
  const int d = threadIdx.x * 4;
  const ushort* cb = cyc + ((long)b * 2048 + c0) * 1280 + d;
  const float* wb = wsum + b * 2048 + c0;
  float4 a = {0.f, 0.f, 0.f, 0.f};
  for (int c = 0; c < 64; c++) {
    const ushort4 u = *(const ushort4*)(cb + (long)c * 1280);
    const float w = wb[c];
    a.x += w * bf2f(u.x); a.y += w * bf2f(u.y);
    a.z += w * bf2f(u.z); a.w += w * bf2f(u.w);
  }
  atomicAdd(&t[b * 1280 + d + 0], a.x);
  atomicAdd(&t[b * 1280 + d + 1], a.y);
  atomicAdd(&t[b * 1280 + d + 2], a.z);
  atomicAdd(&t[b * 1280 + d + 3], a.w);
}

// xcat[b, 1280+d] = mean_s sub16[b,s,d]
__global__ __launch_bounds__(256)
void submean_kernel(const ushort* __restrict__ sub, float* __restrict__ xcat)
{
  const int b = blockIdx.x;
  const int d = blockIdx.y * 256 + threadIdx.x;
  const int s0 = blockIdx.z * 256;
  const ushort* sb = sub + ((long)b * 1024 + s0) * 1280 + d;
  float a = 0.f;
  for (int s = 0; s < 256; s++) a += bf2f(sb[(long)s * 1280]);
  atomicAdd(&xcat[b * 2560 + 1280 + d], a * (1.f / 1024.f));
}

// xcat[b, dp] = (1/1024) * sum_d t[b,d] * Wv[d,dp]
__global__ __launch_bounds__(256)
void xv_kernel(const float* __restrict__ t, const float* __restrict__ Wv,
               float* __restrict__ xcat)
{
  const int b = blockIdx.y;
  const int dp = blockIdx.x * 256 + threadIdx.x;
  __shared__ float tl[1280];
  for (int i = threadIdx.x; i < 1280; i += 256) tl[i] = t[b * 1280 + i];
  __syncthreads();
  float a = 0.f;
  for (int d = 0; d < 1280; d++) a += tl[d] * Wv[(long)d * 1280 + dp];
  xcat[b * 2560 + dp] = a * (1.f / 1024.f);
}

// h1 = relu(xcat @ W1 + b1)
__global__ __launch_bounds__(256)
void mlp1_kernel(const float* __restrict__ xcat, const float* __restrict__ W1,
                 const float* __restrict__ b1, float* __restrict__ h1)
{
  const int b = blockIdx.y;
  const int j = blockIdx.x * 256 + threadIdx.x;
  __shared__ float xl[2560];
  for (int i = threadIdx.x; i < 2560; i += 256) xl[i] = xcat[b * 2560 + i];
  __syncthreads();
  float a = b1[j];
  for (int d = 0; d < 2560; d++) a += xl[d] * W1[(long)d * 512 + j];
  h1[b * 512 + j] = fmaxf(a, 0.f);
}

// h2 = relu(h1 @ W2 + b2); out = sigmoid(h2 @ W3 + b3)
__global__ __launch_bounds__(64)
void mlp23_kernel(const float* __restrict__ h1, const float* __restrict__ W2,
                  const float* __restrict__ b2, const float* __restrict__ W3,
                  const float* __restrict__ b3, float* __restrict__ out)
{
  const int b = blockIdx.x;
  const int j = threadIdx.x;  // 64 threads = 1 wave
  __shared__ float hl[512];
  for (int i = j; i < 512; i += 64) hl[i] = h1[b * 512 + i];
  __syncthreads();
  float a = b2[j];
  for (int d = 0; d < 512; d++) a += hl[d] * W2[d * 64 + j];
  a = fmaxf(a, 0.f);
  float p = a * W3[j];
  #pragma unroll
  for (int o = 1; o < 64; o <<= 1) p += __shfl_xor(p, o);
  if (j == 0) out[b] = 1.f / (1.f + __expf(-(p + b3[0])));
}

extern "C" void kernel_launch(void* const* d_in, const int* in_sizes, int n_in,
                              void* d_out, int out_size, void* d_ws, size_t ws_size,
                              hipStream_t stream)
{
  const float* cyclase   = (const float*)d_in[0];
  const float* substrate = (const float*)d_in[1];
  // d_in[2], d_in[3]: masks — reference's masking is a no-op (replicated bug).
  const float* Wq = (const float*)d_in[4];
  const float* Wk = (const float*)d_in[5];
  const float* Wv = (const float*)d_in[6];
  const float* W1 = (const float*)d_in[7];
  const float* b1 = (const float*)d_in[8];
  const float* W2 = (const float*)d_in[9];
  const float* b2 = (const float*)d_in[10];
  const float* W3 = (const float*)d_in[11];
  const float* b3 = (const float*)d_in[12];
  float* out = (float*)d_out;
  (void)in_sizes; (void)n_in; (void)out_size; (void)ws_size;

  // Workspace (lifetime-aliased, ~193.5 MB):
  //   [0, 84M)            cyc16                     (cvt .. wcyc)
  //   [84M, 151.2M)       sub16(42M)+Mkq(3.3M)   -> S(67.1M) after both dead
  //   [151.2M, 193.1M)    Wq16+Wk16(6.6M)        -> T1(42M) after Mkq-gemm
  //   [193.1M, ...)       wsum/tbuf/xcat/h1
  char* ws = (char*)d_ws;
  ushort* cyc16 = (ushort*)ws;
  char*   base2 = ws + 83886080;
  ushort* sub16 = (ushort*)base2;
  ushort* Mkq   = (ushort*)(base2 + 41943040);
  ushort* S     = (ushort*)base2;
  char*   base3 = base2 + 67108864;
  ushort* T1    = (ushort*)base3;
  ushort* Wq16  = (ushort*)base3;
  ushort* Wk16  = (ushort*)(base3 + 3276800);
  char*   base4 = base3 + 41943040;
  float* wsum = (float*)base4;
  float* tbuf = (float*)(base4 + 131072);
  float* xcat = (float*)(base4 + 131072 + 81920);
  float* h1   = (float*)(base4 + 131072 + 81920 + 163840);

  hipMemsetAsync(wsum, 0, 16 * 2048 * 4, stream);
  hipMemsetAsync(tbuf, 0, 16 * 1280 * 4, stream);
  hipMemsetAsync(xcat, 0, 16 * 2560 * 4, stream);

  cvt_bf16<<<200, 256, 0, stream>>>(Wq, Wq16, 1280l * 1280 / 8);
  cvt_bf16<<<200, 256, 0, stream>>>(Wk, Wk16, 1280l * 1280 / 8);
  cvt_bf16<<<2048, 256, 0, stream>>>(substrate, sub16, 16l * 1024 * 1280 / 8);
  cvt_bf16<<<2048, 256, 0, stream>>>(cyclase, cyc16, 16l * 2048 * 1280 / 8);

  // Mkq = Wk @ Wq^T * (1/sqrt(1280))  [1280,1280]  BN=128: 10 x 5 = 50 blocks
  gemm_d3<128, false><<<50, 512, 0, stream>>>(Wk16, Wq16, Mkq,
      1280, 1280, 10, 5, 0, 0, 0, 0.02795084971874737f);

  submean_kernel<<<dim3(16, 5, 4), 256, 0, stream>>>(sub16, xcat);

  // T1 = sub16 @ Mkq^T  [16384,1280]  BN=128: 10 x 64 = 640 blocks (bx-fast:
  // A-panel hot per XCD, Mkq fully L2-resident)
  gemm_d3<128, false><<<640, 512, 0, stream>>>(sub16, Mkq, T1,
      1280, 1280, 10, 64, 0, 0, 0, 1.0f);

  // S[b] = T1[b] @ cyc16[b]^T  [16,1024,2048]  BN=256: 16 x 8 x 4 = 512
  // blocks (by-fast: cyc16 B-panel reused across consecutive blocks)
  gemm_d3<256, true><<<512, 512, 0, stream>>>(T1, cyc16, S,
      1280, 2048, 8, 4, 1024l * 1280, 2048l * 1280, 1024l * 2048, 1.0f);

  softmax_wsum<<<dim3(16, 32), 256, 0, stream>>>(S, wsum);
  wcyc_kernel<<<dim3(16, 32), 320, 0, stream>>>(cyc16, wsum, tbuf);
  xv_kernel<<<dim3(5, 16), 256, 0, stream>>>(tbuf, Wv, xcat);
  mlp1_kernel<<<dim3(2, 16), 256, 0, stream>>>(xcat, W1, b1, h1);
  mlp23_kernel<<<16, 64, 0, stream>>>(h1, W2, b2, W3, b3, out);
}

// Round 9
// 655.968 us; speedup vs baseline: 1.0881x; 1.0357x over previous
//
#include <hip/hip_runtime.h>
#include <hip/hip_bf16.h>

#define DEV static __device__ __forceinline__

typedef __attribute__((ext_vector_type(16))) float f32x16;
typedef __attribute__((ext_vector_type(8)))  short bf16x8;

DEV ushort f2bf(float f){
  union { float f; unsigned u; } v; v.f = f;
  return (ushort)((v.u + 0x7FFFu + ((v.u >> 16) & 1u)) >> 16);
}
DEV float bf2f(ushort u){
  union { unsigned u; float f; } v; v.u = ((unsigned)u) << 16;
  return v.f;
}

// f32 -> OCP e4m3fn, round-to-nearest, saturating at +-448.
DEV unsigned char f2e4m3(float f){
  union { float f; unsigned u; } v; v.f = f;
  unsigned s = (v.u >> 24) & 0x80;
  float a = fabsf(f);
  if (a >= 448.f) return s | 0x7E;
  if (a < 0.0009765625f) return (unsigned char)s;          // < 2^-10 -> 0
  if (a < 0.015625f) {                                     // subnormal
    int m = (int)rintf(a * 512.f);
    return (unsigned char)(s | (m >= 8 ? 8 : m));
  }
  unsigned ab = v.u & 0x7FFFFFFF;
  unsigned r = ab + 0x0007FFFF + ((ab >> 20) & 1);         // RNE to 3 mant bits
  unsigned e = (r >> 23) - 127 + 7;
  unsigned m = (r >> 20) & 7;
  if (e > 15 || (e == 15 && m > 6)) return s | 0x7E;
  return (unsigned char)(s | (e << 3) | m);
}
DEV float e4m32f(unsigned char c){
  unsigned e = (c >> 3) & 15, m = c & 7;
  float v;
  if (e) { union { unsigned u; float f; } w; w.u = ((e + 120u) << 23) | (m << 20); v = w.f; }
  else v = (float)m * 0.001953125f;
  return (c & 0x80) ? -v : v;
}

// async global->LDS, 16B per lane; LDS dest is wave-uniform base + lane*16.
DEV void gload16(const void* g, void* l) {
  __builtin_amdgcn_global_load_lds(
      (const __attribute__((address_space(1))) unsigned*)g,
      (__attribute__((address_space(3))) unsigned*)l, 16, 0, 0);
}

// ---------------------------------------------------------------------------
// Elementwise f32 -> bf16 (8 elems/thread, grid-stride).
// ---------------------------------------------------------------------------
__global__ __launch_bounds__(256)
void cvt_bf16(const float* __restrict__ src, ushort* __restrict__ dst, long n8)
{
  const long stride = (long)gridDim.x * 256;
  for (long i = (long)blockIdx.x * 256 + threadIdx.x; i < n8; i += stride) {
    const float4 a = *(const float4*)(src + i * 8);
    const float4 b = *(const float4*)(src + i * 8 + 4);
    union { ushort u[8]; uint4 v; } pk;
    pk.u[0] = f2bf(a.x); pk.u[1] = f2bf(a.y); pk.u[2] = f2bf(a.z); pk.u[3] = f2bf(a.w);
    pk.u[4] = f2bf(b.x); pk.u[5] = f2bf(b.y); pk.u[6] = f2bf(b.z); pk.u[7] = f2bf(b.w);
    *(uint4*)(dst + i * 8) = pk.v;
  }
}

// f32 -> e4m3 (x scale), 4/thread grid-stride.
__global__ __launch_bounds__(256)
void cvt_fp8(const float* __restrict__ src, unsigned char* __restrict__ dst,
             long n4, float scale)
{
  const long stride = (long)gridDim.x * 256;
  for (long i = (long)blockIdx.x * 256 + threadIdx.x; i < n4; i += stride) {
    const float4 a = *(const float4*)(src + i * 4);
    uchar4 o;
    o.x = f2e4m3(a.x * scale); o.y = f2e4m3(a.y * scale);
    o.z = f2e4m3(a.z * scale); o.w = f2e4m3(a.w * scale);
    *(uchar4*)(dst + i * 4) = o;
  }
}

// cyclase: f32 row -> fp8 row (x16) + exact f32 rowsum. Wave per row.
__global__ __launch_bounds__(256)
void cyccvt(const float* __restrict__ cyc, unsigned char* __restrict__ cyc8,
            float* __restrict__ gsum)
{
  const int lane = threadIdx.x & 63, wid = threadIdx.x >> 6;
  const long row = (long)blockIdx.x * 4 + wid;   // 32768 rows
  const float* src = cyc + row * 1280;
  unsigned char* dst = cyc8 + row * 1280;
  float s = 0.f;
  #pragma unroll
  for (int i = 0; i < 5; i++) {
    const int d = i * 256 + lane * 4;
    const float4 v = *(const float4*)(src + d);
    s += v.x + v.y + v.z + v.w;
    uchar4 o;
    o.x = f2e4m3(v.x * 16.f); o.y = f2e4m3(v.y * 16.f);
    o.z = f2e4m3(v.z * 16.f); o.w = f2e4m3(v.w * 16.f);
    *(uchar4*)(dst + d) = o;
  }
  #pragma unroll
  for (int o = 1; o < 64; o <<= 1) s += __shfl_xor(s, o);
  if (lane == 0) gsum[row] = s;
}

// ---------------------------------------------------------------------------
// bf16 GEMM 8-phase (r6 structure, BM=128) — used only for Mkq (small).
// ---------------------------------------------------------------------------
__global__ __launch_bounds__(512, 4)
void gemm_mkq(const ushort* __restrict__ A, const ushort* __restrict__ B,
              ushort* __restrict__ C, int K, int N, int nbx, float scale)
{
  __shared__ __align__(16) ushort As[4][4][128][8];
  __shared__ __align__(16) ushort Bs[4][4][128][8];
  const int tid = threadIdx.x, lane = tid & 63, wid = tid >> 6;
  const int wr = wid >> 2, wc = wid & 3;
  const int bx = blockIdx.x % nbx, by = blockIdx.x / nbx;
  const int bm = by * 128, bn = bx * 128;

  f32x16 acc[2];
  #pragma unroll
  for (int i = 0; i < 2; i++)
    #pragma unroll
    for (int e = 0; e < 16; e++) acc[i][e] = 0.f;

  const int kbA = wid >> 1, rqA = wid & 1;
  const ushort* agp = A + (long)(bm + rqA * 64 + lane) * K + kbA * 8;
  const ushort* bgp = B + (long)(bn + rqA * 64 + lane) * K + kbA * 8;
  auto STAGE = [&](int g, int rg) {
    gload16(agp + g * 32, &As[rg][kbA][rqA * 64][0]);
    gload16(bgp + g * 32, &Bs[rg][kbA][rqA * 64][0]);
  };
  const int NG = K >> 5;
  STAGE(0, 0); STAGE(1, 1);
  asm volatile("s_waitcnt vmcnt(2)" ::: "memory");
  __builtin_amdgcn_s_barrier();
  const int lkh = lane >> 5, lr = lane & 31;
  auto GROUP = [&](int g, int rg, int rg2) {
    bf16x8 av[2][2], bv[2];
    #pragma unroll
    for (int kf = 0; kf < 2; kf++) {
      #pragma unroll
      for (int mi = 0; mi < 2; mi++)
        av[mi][kf] = *(const bf16x8*)&As[rg][kf * 2 + lkh][wr * 64 + mi * 32 + lr][0];
      bv[kf] = *(const bf16x8*)&Bs[rg][kf * 2 + lkh][wc * 32 + lr][0];
    }
    if (g + 2 < NG) STAGE(g + 2, rg2);
    __builtin_amdgcn_s_barrier();
    __builtin_amdgcn_s_setprio(1);
    #pragma unroll
    for (int mi = 0; mi < 2; mi++)
      #pragma unroll
      for (int kf = 0; kf < 2; kf++)
        acc[mi] = __builtin_amdgcn_mfma_f32_32x32x16_bf16(av[mi][kf], bv[kf], acc[mi], 0, 0, 0);
    __builtin_amdgcn_s_setprio(0);
    if (g + 2 < NG)      asm volatile("s_waitcnt vmcnt(2)" ::: "memory");
    else if (g + 1 < NG) asm volatile("s_waitcnt vmcnt(0)" ::: "memory");
    __builtin_amdgcn_s_barrier();
  };
  for (int g = 0; g < NG; g += 4) {
    GROUP(g, 0, 2); GROUP(g + 1, 1, 3); GROUP(g + 2, 2, 0); GROUP(g + 3, 3, 1);
  }
  #pragma unroll
  for (int mi = 0; mi < 2; mi++)
    #pragma unroll
    for (int rr = 0; rr < 16; rr++) {
      const int row = bm + wr * 64 + mi * 32 + (rr & 3) + 8 * (rr >> 2) + 4 * lkh;
      const int col = bn + wc * 32 + lr;
      C[(long)row * N + col] = f2bf(acc[mi][rr] * scale);
    }
}

// mcol[d] = mean_j Mkq[j][d]
__global__ __launch_bounds__(256)
void colmean(const ushort* __restrict__ Mkq, float* __restrict__ mcol)
{
  const int d = blockIdx.x * 256 + threadIdx.x;
  float s = 0.f;
  for (int j = 0; j < 1280; j++) s += bf2f(Mkq[(long)j * 1280 + d]);
  mcol[d] = s * (1.f / 1280.f);
}

// M2_8[j][d] = e4m3((Mkq[j][d] - mcol[d]) * 2^19)
__global__ __launch_bounds__(256)
void m2cvt(const ushort* __restrict__ Mkq, const float* __restrict__ mcol,
           unsigned char* __restrict__ M2)
{
  const int j = blockIdx.x;
  for (int d = threadIdx.x; d < 1280; d += 256)
    M2[(long)j * 1280 + d] = f2e4m3((bf2f(Mkq[(long)j * 1280 + d]) - mcol[d]) * 524288.f);
}

// tbar[s] = sub16[s,:] . mcol  (exact rank-1 row term). Wave per row.
__global__ __launch_bounds__(256)
void tbar_gemv(const ushort* __restrict__ sub16, const float* __restrict__ mcol,
               float* __restrict__ tbar)
{
  __shared__ float mc[1280];
  for (int i = threadIdx.x; i < 1280; i += 256) mc[i] = mcol[i];
  __syncthreads();
  const int lane = threadIdx.x & 63, wid = threadIdx.x >> 6;
  const long row = (long)blockIdx.x * 4 + wid;   // 16384 rows
  const ushort* sp = sub16 + row * 1280;
  float d = 0.f;
  for (int c = lane; c < 160; c += 64) {
    bf16x8 v = *(const bf16x8*)(sp + c * 8);
    const ushort* vu = (const ushort*)&v;
    #pragma unroll
    for (int j = 0; j < 8; j++) d += bf2f(vu[j]) * mc[c * 8 + j];
  }
  #pragma unroll
  for (int o = 1; o < 64; o <<= 1) d += __shfl_xor(d, o);
  if (lane == 0) tbar[row] = d;
}

// ---------------------------------------------------------------------------
// fp8 GEMM, 8-phase (r6 skeleton): D = A8 @ B8^T, B8 is [N][K] K-contiguous
// bytes. BM=BN=256, 8 waves (2x4, wave 128x64), MFMA 32x32x16_fp8_fp8,
// BK=64 (4 instrs), LDS 4-slot ring [kf 0..3][256 rows][16B] (linear DMA,
// b64 frag reads: 4-way bank conflict, accepted). Counted vmcnt(4), two
// phases/group, one STAGE_A / STAGE_B per phase — identical sync to r6.
// MODE 0: C = bf16( acc*2^-16 + tbar[z*1024+row]*gsum[z*2048+col] )   (S)
// MODE 1: C = e4m3( acc * 2^-11 )                                     (T1')
// ---------------------------------------------------------------------------
template<int MODE, bool BY_FAST>
__global__ __launch_bounds__(512, 2)
void gemm_f8(const unsigned char* __restrict__ A, const unsigned char* __restrict__ B,
             void* __restrict__ Cv, int K, int N, int nbx, int nby,
             long sA, long sB, long sC,
             const float* __restrict__ tbar, const float* __restrict__ gsum)
{
  __shared__ __align__(16) unsigned char As[4][4][256][16];  // 64 KB
  __shared__ __align__(16) unsigned char Bs[4][4][256][16];  // 64 KB
  const int tid = threadIdx.x, lane = tid & 63, wid = tid >> 6;
  const int wr = wid >> 2, wc = wid & 3;

  const int nwg = gridDim.x;
  const int q = nwg >> 3, r = nwg & 7;
  const int xcd = blockIdx.x & 7, lid = blockIdx.x >> 3;
  const int id = (xcd < r ? xcd * (q + 1) : r * (q + 1) + (xcd - r) * q) + lid;
  const int per = nbx * nby;
  const int z = id / per, rem = id - z * per;
  const int bx = BY_FAST ? rem / nby : rem % nbx;
  const int by = BY_FAST ? rem % nby : rem / nbx;
  const int bm = by * 256, bn = bx * 256;
  const long Ab = (long)z * sA, Bb = (long)z * sB, Cb = (long)z * sC;

  f32x16 acc[4][2];
  #pragma unroll
  for (int i = 0; i < 4; i++)
    #pragma unroll
    for (int j = 0; j < 2; j++)
      #pragma unroll
      for (int e = 0; e < 16; e++) acc[i][j][e] = 0.f;

  // 16 chunks of 1KB per matrix per group; wave stages {2w,2w+1}.
  const int c0 = wid * 2, c1 = wid * 2 + 1;
  const int kb0 = c0 >> 2, rq0 = c0 & 3, kb1 = c1 >> 2, rq1 = c1 & 3;
  const unsigned char* ag0 = A + Ab + (long)(bm + rq0 * 64 + lane) * K + kb0 * 16;
  const unsigned char* ag1 = A + Ab + (long)(bm + rq1 * 64 + lane) * K + kb1 * 16;
  const unsigned char* bg0 = B + Bb + (long)(bn + rq0 * 64 + lane) * K + kb0 * 16;
  const unsigned char* bg1 = B + Bb + (long)(bn + rq1 * 64 + lane) * K + kb1 * 16;
  auto STAGE_A = [&](int g, int rg) {
    gload16(ag0 + g * 64, &As[rg][kb0][rq0 * 64][0]);
    gload16(ag1 + g * 64, &As[rg][kb1][rq1 * 64][0]);
  };
  auto STAGE_B = [&](int g, int rg) {
    gload16(bg0 + g * 64, &Bs[rg][kb0][rq0 * 64][0]);
    gload16(bg1 + g * 64, &Bs[rg][kb1][rq1 * 64][0]);
  };

  const int NG = K >> 6;  // 64-K groups, multiple of 4
  STAGE_A(0, 0); STAGE_B(0, 0); STAGE_A(1, 1); STAGE_B(1, 1);
  asm volatile("s_waitcnt vmcnt(4)" ::: "memory");
  __builtin_amdgcn_s_barrier();

  const int lkh = lane >> 5, lr = lane & 31;

  auto GROUP = [&](int g, int rg, int rg2) {
    const bool pre = (g + 2 < NG);
    long av[2][4], bv[2][4];
    #pragma unroll
    for (int kf = 0; kf < 4; kf++) {
      #pragma unroll
      for (int mi = 0; mi < 2; mi++)
        av[mi][kf] = *(const long*)&As[rg][kf][wr * 128 + mi * 32 + lr][lkh * 8];
      #pragma unroll
      for (int ni = 0; ni < 2; ni++)
        bv[ni][kf] = *(const long*)&Bs[rg][kf][wc * 64 + ni * 32 + lr][lkh * 8];
    }
    if (pre) STAGE_A(g + 2, rg2);
    __builtin_amdgcn_s_barrier();
    __builtin_amdgcn_s_setprio(1);
    #pragma unroll
    for (int kf = 0; kf < 4; kf++)
      #pragma unroll
      for (int mi = 0; mi < 2; mi++)
        #pragma unroll
        for (int ni = 0; ni < 2; ni++)
          acc[mi][ni] = __builtin_amdgcn_mfma_f32_32x32x16_fp8_fp8(av[mi][kf], bv[ni][kf], acc[mi][ni], 0, 0, 0);
    __builtin_amdgcn_s_setprio(0);
    __builtin_amdgcn_s_barrier();
    // beta: m-tiles 2,3 (bv reused)
    #pragma unroll
    for (int kf = 0; kf < 4; kf++)
      #pragma unroll
      for (int mi = 0; mi < 2; mi++)
        av[mi][kf] = *(const long*)&As[rg][kf][wr * 128 + (mi + 2) * 32 + lr][lkh * 8];
    if (pre) STAGE_B(g + 2, rg2);
    __builtin_amdgcn_s_barrier();
    __builtin_amdgcn_s_setprio(1);
    #pragma unroll
    for (int kf = 0; kf < 4; kf++)
      #pragma unroll
      for (int mi = 0; mi < 2; mi++)
        #pragma unroll
        for (int ni = 0; ni < 2; ni++)
          acc[mi + 2][ni] = __builtin_amdgcn_mfma_f32_32x32x16_fp8_fp8(av[mi][kf], bv[ni][kf], acc[mi + 2][ni], 0, 0, 0);
    __builtin_amdgcn_s_setprio(0);
    if (pre)             asm volatile("s_waitcnt vmcnt(4)" ::: "memory");
    else if (g + 1 < NG) asm volatile("s_waitcnt vmcnt(0)" ::: "memory");
    __builtin_amdgcn_s_barrier();
  };

  for (int g = 0; g < NG; g += 4) {
    GROUP(g, 0, 2); GROUP(g + 1, 1, 3); GROUP(g + 2, 2, 0); GROUP(g + 3, 3, 1);
  }

  // C/D 32x32: col=lane&31, row=(reg&3)+8*(reg>>2)+4*(lane>>5)
  #pragma unroll
  for (int mi = 0; mi < 4; mi++)
    #pragma unroll
    for (int ni = 0; ni < 2; ni++)
      #pragma unroll
      for (int rr = 0; rr < 16; rr++) {
        const int row = bm + wr * 128 + mi * 32 + (rr & 3) + 8 * (rr >> 2) + 4 * lkh;
        const int col = bn + wc * 64 + ni * 32 + lr;
        if constexpr (MODE == 0) {
          const float v = acc[mi][ni][rr] * 0x1p-16f
                        + tbar[(long)z * 1024 + row] * gsum[(long)z * 2048 + col];
          ((ushort*)Cv)[Cb + (long)row * N + col] = f2bf(v);
        } else {
          ((unsigned char*)Cv)[Cb + (long)row * N + col] = f2e4m3(acc[mi][ni][rr] * 0x1p-11f);
        }
      }
}

// ---------------------------------------------------------------------------
// Softmax over c per (b,s) row of S (bf16); wsum[b,c] += softmax row.
// ---------------------------------------------------------------------------
__global__ __launch_bounds__(256)
void softmax_wsum(const ushort* __restrict__ S, float* __restrict__ wsum)
{
  const int b = blockIdx.x;
  const int s0 = blockIdx.y * 32;
  const int lane = threadIdx.x & 63;
  const int w = threadIdx.x >> 6;
  __shared__ float red[4][2048];
  const ushort* Sb = S + (((long)b * 1024) + s0 + w * 8) * 2048;

  float acc[32];
  #pragma unroll
  for (int i = 0; i < 32; i++) acc[i] = 0.f;
  for (int r = 0; r < 8; r++) {
    const ushort* row = Sb + (long)r * 2048;
    float v[32];
    #pragma unroll
    for (int i = 0; i < 4; i++) {
      uint4 u = *(const uint4*)(row + i * 512 + lane * 8);
      const ushort* up = (const ushort*)&u;
      #pragma unroll
      for (int j = 0; j < 8; j++) v[i * 8 + j] = bf2f(up[j]);
    }
    float m = v[0];
    #pragma unroll
    for (int i = 1; i < 32; i++) m = fmaxf(m, v[i]);
    #pragma unroll
    for (int o = 1; o < 64; o <<= 1) m = fmaxf(m, __shfl_xor(m, o));
    float ssum = 0.f;
    #pragma unroll
    for (int i = 0; i < 32; i++) { v[i] = __expf(v[i] - m); ssum += v[i]; }
    #pragma unroll
    for (int o = 1; o < 64; o <<= 1) ssum += __shfl_xor(ssum, o);
    const float inv = 1.f / ssum;
    #pragma unroll
    for (int i = 0; i < 32; i++) acc[i] += v[i] * inv;
  }
  #pragma unroll
  for (int i = 0; i < 4; i++)
    #pragma unroll
    for (int j = 0; j < 8; j++)
      red[w][i * 512 + lane * 8 + j] = acc[i * 8 + j];
  __syncthreads();
  float* wb = wsum + b * 2048;
  #pragma unroll
  for (int k = 0; k < 8; k++) {
    const int c = k * 256 + threadIdx.x;
    atomicAdd(&wb[c], red[0][c] + red[1][c] + red[2][c] + red[3][c]);
  }
}

// t[b,d] = sum_c wsum[b,c] * cyc8[b,c,d]/16
__global__ __launch_bounds__(320)
void wcyc_kernel(const unsigned char* __restrict__ cyc8, const float* __restrict__ wsum,
                 float* __restrict__ t)
{
  const int b = blockIdx.x;
  const int c0 = blockIdx.y * 64;
  const int d = threadIdx.x * 4;
  const unsigned char* cb = cyc8 + ((long)b * 2048 + c0) * 1280 + d;
  const float* wb = wsum + b * 2048 + c0;
  float4 a = {0.f, 0.f, 0.f, 0.f};
  for (int c = 0; c < 64; c++) {
    const uchar4 u = *(const uchar4*)(cb + (long)c * 1280);
    const float w = wb[c];
    a.x += w * e4m32f(u.x); a.y += w * e4m32f(u.y);
    a.z += w * e4m32f(u.z); a.w += w * e4m32f(u.w);
  }
  atomicAdd(&t[b * 1280 + d + 0], a.x * 0.0625f);
  atomicAdd(&t[b * 1280 + d + 1], a.y * 0.0625f);
  atomicAdd(&t[b * 1280 + d + 2], a.z * 0.0625f);
  atomicAdd(&t[b * 1280 + d + 3], a.w * 0.0625f);
}

// xcat[b, 1280+d] = mean_s sub16[b,s,d]
__global__ __launch_bounds__(256)
void submean_kernel(const ushort* __restrict__ sub, float* __restrict__ xcat)
{
  const int b = blockIdx.x;
  const int d = blockIdx.y * 256 + threadIdx.x;
  const int s0 = blockIdx.z * 256;
  const ushort* sb = sub + ((long)b * 1024 + s0) * 1280 + d;
  float a = 0.f;
  for (int s = 0; s < 256; s++) a += bf2f(sb[(long)s * 1280]);
  atomicAdd(&xcat[b * 2560 + 1280 + d], a * (1.f / 1024.f));
}

// xcat[b, dp] = (1/1024) * sum_d t[b,d] * Wv[d,dp]
__global__ __launch_bounds__(256)
void xv_kernel(const float* __restrict__ t, const float* __restrict__ Wv,
               float* __restrict__ xcat)
{
  const int b = blockIdx.y;
  const int dp = blockIdx.x * 256 + threadIdx.x;
  __shared__ float tl[1280];
  for (int i = threadIdx.x; i < 1280; i += 256) tl[i] = t[b * 1280 + i];
  __syncthreads();
  float a = 0.f;
  for (int d = 0; d < 1280; d++) a += tl[d] * Wv[(long)d * 1280 + dp];
  xcat[b * 2560 + dp] = a * (1.f / 1024.f);
}

// h1 = relu(xcat @ W1 + b1)
__global__ __launch_bounds__(256)
void mlp1_kernel(const float* __restrict__ xcat, const float* __restrict__ W1,
                 const float* __restrict__ b1, float* __restrict__ h1)
{
  const int b = blockIdx.y;
  const int j = blockIdx.x * 256 + threadIdx.x;
  __shared__ float xl[2560];
  for (int i = threadIdx.x; i < 2560; i += 256) xl[i] = xcat[b * 2560 + i];
  __syncthreads();
  float a = b1[j];
  for (int d = 0; d < 2560; d++) a += xl[d] * W1[(long)d * 512 + j];
  h1[b * 512 + j] = fmaxf(a, 0.f);
}

// h2 = relu(h1 @ W2 + b2); out = sigmoid(h2 @ W3 + b3)
__global__ __launch_bounds__(64)
void mlp23_kernel(const float* __restrict__ h1, const float* __restrict__ W2,
                  const float* __restrict__ b2, const float* __restrict__ W3,
                  const float* __restrict__ b3, float* __restrict__ out)
{
  const int b = blockIdx.x;
  const int j = threadIdx.x;
  __shared__ float hl[512];
  for (int i = j; i < 512; i += 64) hl[i] = h1[b * 512 + i];
  __syncthreads();
  float a = b2[j];
  for (int d = 0; d < 512; d++) a += hl[d] * W2[d * 64 + j];
  a = fmaxf(a, 0.f);
  float p = a * W3[j];
  #pragma unroll
  for (int o = 1; o < 64; o <<= 1) p += __shfl_xor(p, o);
  if (j == 0) out[b] = 1.f / (1.f + __expf(-(p + b3[0])));
}

extern "C" void kernel_launch(void* const* d_in, const int* in_sizes, int n_in,
                              void* d_out, int out_size, void* d_ws, size_t ws_size,
                              hipStream_t stream)
{
  const float* cyclase   = (const float*)d_in[0];
  const float* substrate = (const float*)d_in[1];
  const float* Wq = (const float*)d_in[4];
  const float* Wk = (const float*)d_in[5];
  const float* Wv = (const float*)d_in[6];
  const float* W1 = (const float*)d_in[7];
  const float* b1 = (const float*)d_in[8];
  const float* W2 = (const float*)d_in[9];
  const float* b2 = (const float*)d_in[10];
  const float* W3 = (const float*)d_in[11];
  const float* b3 = (const float*)d_in[12];
  float* out = (float*)d_out;
  (void)in_sizes; (void)n_in; (void)out_size; (void)ws_size;

  // Workspace (~138 MB, lifetime-aliased):
  //  [0,42M)   cyc8                                        (cyccvt .. wcyc)
  //  [42M,~115M) region2: sub16(42M)+Mkq(3.3M)+Wq16+Wk16(6.6M)+sub8(21M)
  //             -> S bf16 (67.1M) overlays after all are dead (pre S-GEMM)
  //  [115M..)  T1'8(21M), M2_8(1.6M), mcol, tbar, gsum, wsum, tbuf, xcat, h1
  char* ws = (char*)d_ws;
  unsigned char* cyc8 = (unsigned char*)ws;
  char* A2 = ws + 41943040;
  ushort* sub16 = (ushort*)A2;
  ushort* Mkq   = (ushort*)(A2 + 41943040);
  ushort* Wq16  = (ushort*)(A2 + 41943040 + 3276800);
  ushort* Wk16  = (ushort*)(A2 + 41943040 + 2 * 3276800);
  unsigned char* sub8 = (unsigned char*)(A2 + 41943040 + 3 * 3276800);
  ushort* S = (ushort*)A2;                       // overlays region2
  char* B2 = A2 + 41943040 + 3 * 3276800 + 20971520;  // = A2 + 72744960
  unsigned char* T1p8 = (unsigned char*)B2;
  unsigned char* M2_8 = (unsigned char*)(B2 + 20971520);
  char* C2 = B2 + 20971520 + 1638400;
  float* mcol = (float*)C2;
  float* tbar = (float*)(C2 + 8192);
  float* gsum = (float*)(C2 + 8192 + 65536);
  float* wsum = (float*)(C2 + 8192 + 65536 + 131072);
  float* tbuf = (float*)(C2 + 8192 + 65536 + 2 * 131072);
  float* xcat = (float*)(C2 + 8192 + 65536 + 2 * 131072 + 81920);
  float* h1   = (float*)(C2 + 8192 + 65536 + 2 * 131072 + 81920 + 163840);

  hipMemsetAsync(wsum, 0, 16 * 2048 * 4, stream);
  hipMemsetAsync(tbuf, 0, 16 * 1280 * 4, stream);
  hipMemsetAsync(xcat, 0, 16 * 2560 * 4, stream);

  cvt_bf16<<<200, 256, 0, stream>>>(Wq, Wq16, 1280l * 1280 / 8);
  cvt_bf16<<<200, 256, 0, stream>>>(Wk, Wk16, 1280l * 1280 / 8);
  cvt_bf16<<<2048, 256, 0, stream>>>(substrate, sub16, 16l * 1024 * 1280 / 8);
  cvt_fp8<<<2048, 256, 0, stream>>>(substrate, sub8, 16l * 1024 * 1280 / 4, 16.f);
  cyccvt<<<8192, 256, 0, stream>>>(cyclase, cyc8, gsum);

  // Mkq = Wk @ Wq^T * (1/sqrt(1280))  [1280,1280] bf16
  gemm_mkq<<<100, 512, 0, stream>>>(Wk16, Wq16, Mkq, 1280, 1280, 10,
                                    0.02795084971874737f);
  colmean<<<5, 256, 0, stream>>>(Mkq, mcol);
  m2cvt<<<1280, 256, 0, stream>>>(Mkq, mcol, M2_8);
  tbar_gemv<<<4096, 256, 0, stream>>>(sub16, mcol, tbar);
  submean_kernel<<<dim3(16, 5, 4), 256, 0, stream>>>(sub16, xcat);

  // T1' = sub8 @ M2_8^T -> fp8 x4096   [16384,1280]
  gemm_f8<1, false><<<320, 512, 0, stream>>>(sub8, M2_8, T1p8,
      1280, 1280, 5, 64, 0, 0, 0, nullptr, nullptr);

  // S[b] = T1'8 @ cyc8^T * 2^-16 + tbar x gsum -> bf16  [16,1024,2048]
  gemm_f8<0, true><<<512, 512, 0, stream>>>(T1p8, cyc8, S,
      1280, 2048, 8, 4, 1024l * 1280, 2048l * 1280, 1024l * 2048, tbar, gsum);

  softmax_wsum<<<dim3(16, 32), 256, 0, stream>>>(S, wsum);
  wcyc_kernel<<<dim3(16, 32), 320, 0, stream>>>(cyc8, wsum, tbuf);
  xv_kernel<<<dim3(5, 16), 256, 0, stream>>>(tbuf, Wv, xcat);
  mlp1_kernel<<<dim3(2, 16), 256, 0, stream>>>(xcat, W1, b1, h1);
  mlp23_kernel<<<16, 64, 0, stream>>>(h1, W2, b2, W3, b3, out);
}

// Round 10
// 525.475 us; speedup vs baseline: 1.3583x; 1.2483x over previous
//
#include <hip/hip_runtime.h>
#include <hip/hip_bf16.h>

#define DEV static __device__ __forceinline__

typedef __attribute__((ext_vector_type(16))) float f32x16;
typedef __attribute__((ext_vector_type(8)))  short bf16x8;

#if defined(__has_builtin)
#  if __has_builtin(__builtin_amdgcn_cvt_pk_fp8_f32) && __has_builtin(__builtin_amdgcn_cvt_f32_fp8)
#    define HW_FP8 1
#  endif
#endif

DEV ushort f2bf(float f){
  union { float f; unsigned u; } v; v.f = f;
  return (ushort)((v.u + 0x7FFFu + ((v.u >> 16) & 1u)) >> 16);
}
DEV float bf2f(ushort u){
  union { unsigned u; float f; } v; v.u = ((unsigned)u) << 16;
  return v.f;
}

// f32 -> OCP e4m3fn (software fallback), RNE, saturating.
DEV unsigned char f2e4m3_sw(float f){
  union { float f; unsigned u; } v; v.f = f;
  unsigned s = (v.u >> 24) & 0x80;
  float a = fabsf(f);
  if (a >= 448.f) return s | 0x7E;
  if (a < 0.0009765625f) return (unsigned char)s;
  if (a < 0.015625f) {
    int m = (int)rintf(a * 512.f);
    return (unsigned char)(s | (m >= 8 ? 8 : m));
  }
  unsigned ab = v.u & 0x7FFFFFFF;
  unsigned r = ab + 0x0007FFFF + ((ab >> 20) & 1);
  unsigned e = (r >> 23) - 127 + 7;
  unsigned m = (r >> 20) & 7;
  if (e > 15 || (e == 15 && m > 6)) return s | 0x7E;
  return (unsigned char)(s | (e << 3) | m);
}
DEV float e4m32f_sw(unsigned char c){
  unsigned e = (c >> 3) & 15, m = c & 7;
  float v;
  if (e) { union { unsigned u; float f; } w; w.u = ((e + 120u) << 23) | (m << 20); v = w.f; }
  else v = (float)m * 0.001953125f;
  return (c & 0x80) ? -v : v;
}

// pack 4 f32 -> 4 e4m3 bytes (hw v_cvt_pk_fp8_f32 when available)
DEV unsigned pack4_fp8(float a, float b, float c, float d){
#ifdef HW_FP8
  int v = __builtin_amdgcn_cvt_pk_fp8_f32(a, b, 0, false);
  v = __builtin_amdgcn_cvt_pk_fp8_f32(c, d, v, true);
  return (unsigned)v;
#else
  return (unsigned)f2e4m3_sw(a) | ((unsigned)f2e4m3_sw(b) << 8)
       | ((unsigned)f2e4m3_sw(c) << 16) | ((unsigned)f2e4m3_sw(d) << 24);
#endif
}
DEV unsigned char enc_fp8(float a){
#ifdef HW_FP8
  return (unsigned char)(__builtin_amdgcn_cvt_pk_fp8_f32(a, a, 0, false) & 0xFF);
#else
  return f2e4m3_sw(a);
#endif
}

// async global->LDS, 16B per lane; LDS dest is wave-uniform base + lane*16.
DEV void gload16(const void* g, void* l) {
  __builtin_amdgcn_global_load_lds(
      (const __attribute__((address_space(1))) unsigned*)g,
      (__attribute__((address_space(3))) unsigned*)l, 16, 0, 0);
}

// ---------------------------------------------------------------------------
// Elementwise f32 -> bf16 (8 elems/thread, grid-stride).  (Wq/Wk only now.)
// ---------------------------------------------------------------------------
__global__ __launch_bounds__(256)
void cvt_bf16(const float* __restrict__ src, ushort* __restrict__ dst, long n8)
{
  const long stride = (long)gridDim.x * 256;
  for (long i = (long)blockIdx.x * 256 + threadIdx.x; i < n8; i += stride) {
    const float4 a = *(const float4*)(src + i * 8);
    const float4 b = *(const float4*)(src + i * 8 + 4);
    union { ushort u[8]; uint4 v; } pk;
    pk.u[0] = f2bf(a.x); pk.u[1] = f2bf(a.y); pk.u[2] = f2bf(a.z); pk.u[3] = f2bf(a.w);
    pk.u[4] = f2bf(b.x); pk.u[5] = f2bf(b.y); pk.u[6] = f2bf(b.z); pk.u[7] = f2bf(b.w);
    *(uint4*)(dst + i * 8) = pk.v;
  }
}

// f32 -> e4m3 (x scale), 4/thread grid-stride, hw pack.
__global__ __launch_bounds__(256)
void cvt_fp8(const float* __restrict__ src, unsigned* __restrict__ dst,
             long n4, float scale)
{
  const long stride = (long)gridDim.x * 256;
  for (long i = (long)blockIdx.x * 256 + threadIdx.x; i < n4; i += stride) {
    const float4 a = *(const float4*)(src + i * 4);
    dst[i] = pack4_fp8(a.x * scale, a.y * scale, a.z * scale, a.w * scale);
  }
}

// cyclase: f32 row -> fp8 row (x16) + exact f32 rowsum. Wave per row.
__global__ __launch_bounds__(256)
void cyccvt(const float* __restrict__ cyc, unsigned* __restrict__ cyc8w,
            float* __restrict__ gsum)
{
  const int lane = threadIdx.x & 63, wid = threadIdx.x >> 6;
  const long row = (long)blockIdx.x * 4 + wid;   // 32768 rows
  const float* src = cyc + row * 1280;
  unsigned* dst = cyc8w + row * 320;
  float s = 0.f;
  #pragma unroll
  for (int i = 0; i < 5; i++) {
    const int d = i * 256 + lane * 4;
    const float4 v = *(const float4*)(src + d);
    s += v.x + v.y + v.z + v.w;
    dst[d >> 2] = pack4_fp8(v.x * 16.f, v.y * 16.f, v.z * 16.f, v.w * 16.f);
  }
  #pragma unroll
  for (int o = 1; o < 64; o <<= 1) s += __shfl_xor(s, o);
  if (lane == 0) gsum[row] = s;
}

// ---------------------------------------------------------------------------
// bf16 GEMM 8-phase (r6 structure, BM=128) — used only for Mkq (small).
// ---------------------------------------------------------------------------
__global__ __launch_bounds__(512, 4)
void gemm_mkq(const ushort* __restrict__ A, const ushort* __restrict__ B,
              ushort* __restrict__ C, int K, int N, int nbx, float scale)
{
  __shared__ __align__(16) ushort As[4][4][128][8];
  __shared__ __align__(16) ushort Bs[4][4][128][8];
  const int tid = threadIdx.x, lane = tid & 63, wid = tid >> 6;
  const int wr = wid >> 2, wc = wid & 3;
  const int bx = blockIdx.x % nbx, by = blockIdx.x / nbx;
  const int bm = by * 128, bn = bx * 128;

  f32x16 acc[2];
  #pragma unroll
  for (int i = 0; i < 2; i++)
    #pragma unroll
    for (int e = 0; e < 16; e++) acc[i][e] = 0.f;

  const int kbA = wid >> 1, rqA = wid & 1;
  const ushort* agp = A + (long)(bm + rqA * 64 + lane) * K + kbA * 8;
  const ushort* bgp = B + (long)(bn + rqA * 64 + lane) * K + kbA * 8;
  auto STAGE = [&](int g, int rg) {
    gload16(agp + g * 32, &As[rg][kbA][rqA * 64][0]);
    gload16(bgp + g * 32, &Bs[rg][kbA][rqA * 64][0]);
  };
  const int NG = K >> 5;
  STAGE(0, 0); STAGE(1, 1);
  asm volatile("s_waitcnt vmcnt(2)" ::: "memory");
  __builtin_amdgcn_s_barrier();
  const int lkh = lane >> 5, lr = lane & 31;
  auto GROUP = [&](int g, int rg, int rg2) {
    bf16x8 av[2][2], bv[2];
    #pragma unroll
    for (int kf = 0; kf < 2; kf++) {
      #pragma unroll
      for (int mi = 0; mi < 2; mi++)
        av[mi][kf] = *(const bf16x8*)&As[rg][kf * 2 + lkh][wr * 64 + mi * 32 + lr][0];
      bv[kf] = *(const bf16x8*)&Bs[rg][kf * 2 + lkh][wc * 32 + lr][0];
    }
    if (g + 2 < NG) STAGE(g + 2, rg2);
    __builtin_amdgcn_s_barrier();
    __builtin_amdgcn_s_setprio(1);
    #pragma unroll
    for (int mi = 0; mi < 2; mi++)
      #pragma unroll
      for (int kf = 0; kf < 2; kf++)
        acc[mi] = __builtin_amdgcn_mfma_f32_32x32x16_bf16(av[mi][kf], bv[kf], acc[mi], 0, 0, 0);
    __builtin_amdgcn_s_setprio(0);
    if (g + 2 < NG)      asm volatile("s_waitcnt vmcnt(2)" ::: "memory");
    else if (g + 1 < NG) asm volatile("s_waitcnt vmcnt(0)" ::: "memory");
    __builtin_amdgcn_s_barrier();
  };
  for (int g = 0; g < NG; g += 4) {
    GROUP(g, 0, 2); GROUP(g + 1, 1, 3); GROUP(g + 2, 2, 0); GROUP(g + 3, 3, 1);
  }
  #pragma unroll
  for (int mi = 0; mi < 2; mi++)
    #pragma unroll
    for (int rr = 0; rr < 16; rr++) {
      const int row = bm + wr * 64 + mi * 32 + (rr & 3) + 8 * (rr >> 2) + 4 * lkh;
      const int col = bn + wc * 32 + lr;
      C[(long)row * N + col] = f2bf(acc[mi][rr] * scale);
    }
}

// mcol[d] += partial col-mean.  Grid (5, 32): 5 d-blocks x 32 row-chunks of 40.
// (r9's 5-block serial version was the hidden ~200us elephant.)
__global__ __launch_bounds__(256)
void colmean(const ushort* __restrict__ Mkq, float* __restrict__ mcol)
{
  const int d = blockIdx.x * 256 + threadIdx.x;
  const int r0 = blockIdx.y * 40;
  float s = 0.f;
  for (int j = 0; j < 40; j++) s += bf2f(Mkq[(long)(r0 + j) * 1280 + d]);
  atomicAdd(&mcol[d], s * (1.f / 1280.f));
}

// M2_8[j][d] = e4m3((Mkq[j][d] - mcol[d]) * 2^19), 4 cols/thread, hw pack.
__global__ __launch_bounds__(320)
void m2cvt(const ushort* __restrict__ Mkq, const float* __restrict__ mcol,
           unsigned* __restrict__ M2w)
{
  const int j = blockIdx.x;
  const int d = threadIdx.x * 4;
  const ushort* mr = Mkq + (long)j * 1280 + d;
  const float* mc = mcol + d;
  M2w[j * 320 + threadIdx.x] = pack4_fp8(
      (bf2f(mr[0]) - mc[0]) * 524288.f, (bf2f(mr[1]) - mc[1]) * 524288.f,
      (bf2f(mr[2]) - mc[2]) * 524288.f, (bf2f(mr[3]) - mc[3]) * 524288.f);
}

// tbar[s] = substrate[s,:] . mcol  (exact rank-1 row term). Wave per row, f32.
__global__ __launch_bounds__(256)
void tbar_gemv(const float* __restrict__ sub, const float* __restrict__ mcol,
               float* __restrict__ tbar)
{
  __shared__ float mc[1280];
  for (int i = threadIdx.x; i < 1280; i += 256) mc[i] = mcol[i];
  __syncthreads();
  const int lane = threadIdx.x & 63, wid = threadIdx.x >> 6;
  const long row = (long)blockIdx.x * 4 + wid;   // 16384 rows
  const float4* sp = (const float4*)(sub + row * 1280);
  float d = 0.f;
  #pragma unroll
  for (int i = 0; i < 5; i++) {
    const float4 v = sp[i * 64 + lane];
    const int c = (i * 64 + lane) * 4;
    d += v.x * mc[c] + v.y * mc[c + 1] + v.z * mc[c + 2] + v.w * mc[c + 3];
  }
  #pragma unroll
  for (int o = 1; o < 64; o <<= 1) d += __shfl_xor(d, o);
  if (lane == 0) tbar[row] = d;
}

// ---------------------------------------------------------------------------
// fp8 GEMM, 8-phase (r9 kernel, unchanged core): D = A8 @ B8^T, B8 [N][K].
// MODE 0: C = bf16( acc*2^-16 + tbar[z*1024+row]*gsum[z*2048+col] )   (S)
// MODE 1: C = e4m3( acc * 2^-11 )                                     (T1')
// ---------------------------------------------------------------------------
template<int MODE, bool BY_FAST>
__global__ __launch_bounds__(512, 2)
void gemm_f8(const unsigned char* __restrict__ A, const unsigned char* __restrict__ B,
             void* __restrict__ Cv, int K, int N, int nbx, int nby,
             long sA, long sB, long sC,
             const float* __restrict__ tbar, const float* __restrict__ gsum)
{
  __shared__ __align__(16) unsigned char As[4][4][256][16];  // 64 KB
  __shared__ __align__(16) unsigned char Bs[4][4][256][16];  // 64 KB
  const int tid = threadIdx.x, lane = tid & 63, wid = tid >> 6;
  const int wr = wid >> 2, wc = wid & 3;

  const int nwg = gridDim.x;
  const int q = nwg >> 3, r = nwg & 7;
  const int xcd = blockIdx.x & 7, lid = blockIdx.x >> 3;
  const int id = (xcd < r ? xcd * (q + 1) : r * (q + 1) + (xcd - r) * q) + lid;
  const int per = nbx * nby;
  const int z = id / per, rem = id - z * per;
  const int bx = BY_FAST ? rem / nby : rem % nbx;
  const int by = BY_FAST ? rem % nby : rem / nbx;
  const int bm = by * 256, bn = bx * 256;
  const long Ab = (long)z * sA, Bb = (long)z * sB, Cb = (long)z * sC;

  f32x16 acc[4][2];
  #pragma unroll
  for (int i = 0; i < 4; i++)
    #pragma unroll
    for (int j = 0; j < 2; j++)
      #pragma unroll
      for (int e = 0; e < 16; e++) acc[i][j][e] = 0.f;

  const int c0 = wid * 2, c1 = wid * 2 + 1;
  const int kb0 = c0 >> 2, rq0 = c0 & 3, kb1 = c1 >> 2, rq1 = c1 & 3;
  const unsigned char* ag0 = A + Ab + (long)(bm + rq0 * 64 + lane) * K + kb0 * 16;
  const unsigned char* ag1 = A + Ab + (long)(bm + rq1 * 64 + lane) * K + kb1 * 16;
  const unsigned char* bg0 = B + Bb + (long)(bn + rq0 * 64 + lane) * K + kb0 * 16;
  const unsigned char* bg1 = B + Bb + (long)(bn + rq1 * 64 + lane) * K + kb1 * 16;
  auto STAGE_A = [&](int g, int rg) {
    gload16(ag0 + g * 64, &As[rg][kb0][rq0 * 64][0]);
    gload16(ag1 + g * 64, &As[rg][kb1][rq1 * 64][0]);
  };
  auto STAGE_B = [&](int g, int rg) {
    gload16(bg0 + g * 64, &Bs[rg][kb0][rq0 * 64][0]);
    gload16(bg1 + g * 64, &Bs[rg][kb1][rq1 * 64][0]);
  };

  const int NG = K >> 6;  // 64-K groups, multiple of 4
  STAGE_A(0, 0); STAGE_B(0, 0); STAGE_A(1, 1); STAGE_B(1, 1);
  asm volatile("s_waitcnt vmcnt(4)" ::: "memory");
  __builtin_amdgcn_s_barrier();

  const int lkh = lane >> 5, lr = lane & 31;

  auto GROUP = [&](int g, int rg, int rg2) {
    const bool pre = (g + 2 < NG);
    long av[2][4], bv[2][4];
    #pragma unroll
    for (int kf = 0; kf < 4; kf++) {
      #pragma unroll
      for (int mi = 0; mi < 2; mi++)
        av[mi][kf] = *(const long*)&As[rg][kf][wr * 128 + mi * 32 + lr][lkh * 8];
      #pragma unroll
      for (int ni = 0; ni < 2; ni++)
        bv[ni][kf] = *(const long*)&Bs[rg][kf][wc * 64 + ni * 32 + lr][lkh * 8];
    }
    if (pre) STAGE_A(g + 2, rg2);
    __builtin_amdgcn_s_barrier();
    __builtin_amdgcn_s_setprio(1);
    #pragma unroll
    for (int kf = 0; kf < 4; kf++)
      #pragma unroll
      for (int mi = 0; mi < 2; mi++)
        #pragma unroll
        for (int ni = 0; ni < 2; ni++)
          acc[mi][ni] = __builtin_amdgcn_mfma_f32_32x32x16_fp8_fp8(av[mi][kf], bv[ni][kf], acc[mi][ni], 0, 0, 0);
    __builtin_amdgcn_s_setprio(0);
    __builtin_amdgcn_s_barrier();
    #pragma unroll
    for (int kf = 0; kf < 4; kf++)
      #pragma unroll
      for (int mi = 0; mi < 2; mi++)
        av[mi][kf] = *(const long*)&As[rg][kf][wr * 128 + (mi + 2) * 32 + lr][lkh * 8];
    if (pre) STAGE_B(g + 2, rg2);
    __builtin_amdgcn_s_barrier();
    __builtin_amdgcn_s_setprio(1);
    #pragma unroll
    for (int kf = 0; kf < 4; kf++)
      #pragma unroll
      for (int mi = 0; mi < 2; mi++)
        #pragma unroll
        for (int ni = 0; ni < 2; ni++)
          acc[mi + 2][ni] = __builtin_amdgcn_mfma_f32_32x32x16_fp8_fp8(av[mi][kf], bv[ni][kf], acc[mi + 2][ni], 0, 0, 0);
    __builtin_amdgcn_s_setprio(0);
    if (pre)             asm volatile("s_waitcnt vmcnt(4)" ::: "memory");
    else if (g + 1 < NG) asm volatile("s_waitcnt vmcnt(0)" ::: "memory");
    __builtin_amdgcn_s_barrier();
  };

  for (int g = 0; g < NG; g += 4) {
    GROUP(g, 0, 2); GROUP(g + 1, 1, 3); GROUP(g + 2, 2, 0); GROUP(g + 3, 3, 1);
  }

  // C/D 32x32: col=lane&31, row=(reg&3)+8*(reg>>2)+4*(lane>>5)
  #pragma unroll
  for (int mi = 0; mi < 4; mi++)
    #pragma unroll
    for (int ni = 0; ni < 2; ni++)
      #pragma unroll
      for (int rr = 0; rr < 16; rr++) {
        const int row = bm + wr * 128 + mi * 32 + (rr & 3) + 8 * (rr >> 2) + 4 * lkh;
        const int col = bn + wc * 64 + ni * 32 + lr;
        if constexpr (MODE == 0) {
          const float v = acc[mi][ni][rr] * 0x1p-16f
                        + tbar[(long)z * 1024 + row] * gsum[(long)z * 2048 + col];
          ((ushort*)Cv)[Cb + (long)row * N + col] = f2bf(v);
        } else {
          ((unsigned char*)Cv)[Cb + (long)row * N + col] = enc_fp8(acc[mi][ni][rr] * 0x1p-11f);
        }
      }
}

// ---------------------------------------------------------------------------
// Softmax over c per (b,s) row of S (bf16); wsum[b,c] += softmax row.
// ---------------------------------------------------------------------------
__global__ __launch_bounds__(256)
void softmax_wsum(const ushort* __restrict__ S, float* __restrict__ wsum)
{
  const int b = blockIdx.x;
  const int s0 = blockIdx.y * 32;
  const int lane = threadIdx.x & 63;
  const int w = threadIdx.x >> 6;
  __shared__ float red[4][2048];
  const ushort* Sb = S + (((long)b * 1024) + s0 + w * 8) * 2048;

  float acc[32];
  #pragma unroll
  for (int i = 0; i < 32; i++) acc[i] = 0.f;
  for (int r = 0; r < 8; r++) {
    const ushort* row = Sb + (long)r * 2048;
    float v[32];
    #pragma unroll
    for (int i = 0; i < 4; i++) {
      uint4 u = *(const uint4*)(row + i * 512 + lane * 8);
      const ushort* up = (const ushort*)&u;
      #pragma unroll
      for (int j = 0; j < 8; j++) v[i * 8 + j] = bf2f(up[j]);
    }
    float m = v[0];
    #pragma unroll
    for (int i = 1; i < 32; i++) m = fmaxf(m, v[i]);
    #pragma unroll
    for (int o = 1; o < 64; o <<= 1) m = fmaxf(m, __shfl_xor(m, o));
    float ssum = 0.f;
    #pragma unroll
    for (int i = 0; i < 32; i++) { v[i] = __expf(v[i] - m); ssum += v[i]; }
    #pragma unroll
    for (int o = 1; o < 64; o <<= 1) ssum += __shfl_xor(ssum, o);
    const float inv = 1.f / ssum;
    #pragma unroll
    for (int i = 0; i < 32; i++) acc[i] += v[i] * inv;
  }
  #pragma unroll
  for (int i = 0; i < 4; i++)
    #pragma unroll
    for (int j = 0; j < 8; j++)
      red[w][i * 512 + lane * 8 + j] = acc[i * 8 + j];
  __syncthreads();
  float* wb = wsum + b * 2048;
  #pragma unroll
  for (int k = 0; k < 8; k++) {
    const int c = k * 256 + threadIdx.x;
    atomicAdd(&wb[c], red[0][c] + red[1][c] + red[2][c] + red[3][c]);
  }
}

// t[b,d] = sum_c wsum[b,c] * cyc8[b,c,d]/16   (hw fp8 decode)
__global__ __launch_bounds__(320)
void wcyc_kernel(const unsigned char* __restrict__ cyc8, const float* __restrict__ wsum,
                 float* __restrict__ t)
{
  const int b = blockIdx.x;
  const int c0 = blockIdx.y * 64;
  const int d = threadIdx.x * 4;
  const unsigned char* cb = cyc8 + ((long)b * 2048 + c0) * 1280 + d;
  const float* wb = wsum + b * 2048 + c0;
  float4 a = {0.f, 0.f, 0.f, 0.f};
  for (int c = 0; c < 64; c++) {
    const unsigned u = *(const unsigned*)(cb + (long)c * 1280);
    const float w = wb[c];
#ifdef HW_FP8
    a.x += w * __builtin_amdgcn_cvt_f32_fp8((int)u, 0);
    a.y += w * __builtin_amdgcn_cvt_f32_fp8((int)u, 1);
    a.z += w * __builtin_amdgcn_cvt_f32_fp8((int)u, 2);
    a.w += w * __builtin_amdgcn_cvt_f32_fp8((int)u, 3);
#else
    a.x += w * e4m32f_sw(u & 0xFF);
    a.y += w * e4m32f_sw((u >> 8) & 0xFF);
    a.z += w * e4m32f_sw((u >> 16) & 0xFF);
    a.w += w * e4m32f_sw((u >> 24) & 0xFF);
#endif
  }
  atomicAdd(&t[b * 1280 + d + 0], a.x * 0.0625f);
  atomicAdd(&t[b * 1280 + d + 1], a.y * 0.0625f);
  atomicAdd(&t[b * 1280 + d + 2], a.z * 0.0625f);
  atomicAdd(&t[b * 1280 + d + 3], a.w * 0.0625f);
}

// xcat[b, 1280+d] = mean_s substrate[b,s,d]  (f32 source now)
__global__ __launch_bounds__(256)
void submean_kernel(const float* __restrict__ sub, float* __restrict__ xcat)
{
  const int b = blockIdx.x;
  const int d = blockIdx.y * 256 + threadIdx.x;
  const int s0 = blockIdx.z * 256;
  const float* sb = sub + ((long)b * 1024 + s0) * 1280 + d;
  float a = 0.f;
  for (int s = 0; s < 256; s++) a += sb[(long)s * 1280];
  atomicAdd(&xcat[b * 2560 + 1280 + d], a * (1.f / 1024.f));
}

// xcat[b, dp] = (1/1024) * sum_d t[b,d] * Wv[d,dp]
__global__ __launch_bounds__(256)
void xv_kernel(const float* __restrict__ t, const float* __restrict__ Wv,
               float* __restrict__ xcat)
{
  const int b = blockIdx.y;
  const int dp = blockIdx.x * 256 + threadIdx.x;
  __shared__ float tl[1280];
  for (int i = threadIdx.x; i < 1280; i += 256) tl[i] = t[b * 1280 + i];
  __syncthreads();
  float a = 0.f;
  for (int d = 0; d < 1280; d++) a += tl[d] * Wv[(long)d * 1280 + dp];
  xcat[b * 2560 + dp] = a * (1.f / 1024.f);
}

// h1 = relu(xcat @ W1 + b1)
__global__ __launch_bounds__(256)
void mlp1_kernel(const float* __restrict__ xcat, const float* __restrict__ W1,
                 const float* __restrict__ b1, float* __restrict__ h1)
{
  const int b = blockIdx.y;
  const int j = blockIdx.x * 256 + threadIdx.x;
  __shared__ float xl[2560];
  for (int i = threadIdx.x; i < 2560; i += 256) xl[i] = xcat[b * 2560 + i];
  __syncthreads();
  float a = b1[j];
  for (int d = 0; d < 2560; d++) a += xl[d] * W1[(long)d * 512 + j];
  h1[b * 512 + j] = fmaxf(a, 0.f);
}

// h2 = relu(h1 @ W2 + b2); out = sigmoid(h2 @ W3 + b3)
__global__ __launch_bounds__(64)
void mlp23_kernel(const float* __restrict__ h1, const float* __restrict__ W2,
                  const float* __restrict__ b2, const float* __restrict__ W3,
                  const float* __restrict__ b3, float* __restrict__ out)
{
  const int b = blockIdx.x;
  const int j = threadIdx.x;
  __shared__ float hl[512];
  for (int i = j; i < 512; i += 64) hl[i] = h1[b * 512 + i];
  __syncthreads();
  float a = b2[j];
  for (int d = 0; d < 512; d++) a += hl[d] * W2[d * 64 + j];
  a = fmaxf(a, 0.f);
  float p = a * W3[j];
  #pragma unroll
  for (int o = 1; o < 64; o <<= 1) p += __shfl_xor(p, o);
  if (j == 0) out[b] = 1.f / (1.f + __expf(-(p + b3[0])));
}

extern "C" void kernel_launch(void* const* d_in, const int* in_sizes, int n_in,
                              void* d_out, int out_size, void* d_ws, size_t ws_size,
                              hipStream_t stream)
{
  const float* cyclase   = (const float*)d_in[0];
  const float* substrate = (const float*)d_in[1];
  const float* Wq = (const float*)d_in[4];
  const float* Wk = (const float*)d_in[5];
  const float* Wv = (const float*)d_in[6];
  const float* W1 = (const float*)d_in[7];
  const float* b1 = (const float*)d_in[8];
  const float* W2 = (const float*)d_in[9];
  const float* b2 = (const float*)d_in[10];
  const float* W3 = (const float*)d_in[11];
  const float* b3 = (const float*)d_in[12];
  float* out = (float*)d_out;
  (void)in_sizes; (void)n_in; (void)out_size; (void)ws_size;

  // Workspace (same offsets as r9; sub16 slot now unused):
  //  [0,42M)   cyc8                                     (cyccvt .. wcyc)
  //  [42M,..)  region2: Mkq/Wq16/Wk16/sub8 -> S bf16 overlays after all dead
  //  [~115M..) T1'8, M2_8, mcol, tbar, gsum, wsum, tbuf, xcat, h1
  char* ws = (char*)d_ws;
  unsigned char* cyc8 = (unsigned char*)ws;
  char* A2 = ws + 41943040;
  ushort* Mkq   = (ushort*)(A2 + 41943040);
  ushort* Wq16  = (ushort*)(A2 + 41943040 + 3276800);
  ushort* Wk16  = (ushort*)(A2 + 41943040 + 2 * 3276800);
  unsigned char* sub8 = (unsigned char*)(A2 + 41943040 + 3 * 3276800);
  ushort* S = (ushort*)A2;                       // overlays region2
  char* B2 = A2 + 41943040 + 3 * 3276800 + 20971520;
  unsigned char* T1p8 = (unsigned char*)B2;
  unsigned char* M2_8 = (unsigned char*)(B2 + 20971520);
  char* C2 = B2 + 20971520 + 1638400;
  float* mcol = (float*)C2;
  float* tbar = (float*)(C2 + 8192);
  float* gsum = (float*)(C2 + 8192 + 65536);
  float* wsum = (float*)(C2 + 8192 + 65536 + 131072);
  float* tbuf = (float*)(C2 + 8192 + 65536 + 2 * 131072);
  float* xcat = (float*)(C2 + 8192 + 65536 + 2 * 131072 + 81920);
  float* h1   = (float*)(C2 + 8192 + 65536 + 2 * 131072 + 81920 + 163840);

  hipMemsetAsync(mcol, 0, 1280 * 4, stream);
  hipMemsetAsync(wsum, 0, 16 * 2048 * 4, stream);
  hipMemsetAsync(tbuf, 0, 16 * 1280 * 4, stream);
  hipMemsetAsync(xcat, 0, 16 * 2560 * 4, stream);

  cvt_bf16<<<200, 256, 0, stream>>>(Wq, Wq16, 1280l * 1280 / 8);
  cvt_bf16<<<200, 256, 0, stream>>>(Wk, Wk16, 1280l * 1280 / 8);
  cvt_fp8<<<2048, 256, 0, stream>>>(substrate, (unsigned*)sub8,
                                    16l * 1024 * 1280 / 4, 16.f);
  cyccvt<<<8192, 256, 0, stream>>>(cyclase, (unsigned*)cyc8, gsum);

  // Mkq = Wk @ Wq^T * (1/sqrt(1280))  [1280,1280] bf16
  gemm_mkq<<<100, 512, 0, stream>>>(Wk16, Wq16, Mkq, 1280, 1280, 10,
                                    0.02795084971874737f);
  colmean<<<dim3(5, 32), 256, 0, stream>>>(Mkq, mcol);
  m2cvt<<<1280, 320, 0, stream>>>(Mkq, mcol, (unsigned*)M2_8);
  tbar_gemv<<<4096, 256, 0, stream>>>(substrate, mcol, tbar);
  submean_kernel<<<dim3(16, 5, 4), 256, 0, stream>>>(substrate, xcat);

  // T1' = sub8 @ M2_8^T -> fp8 x4096   [16384,1280]
  gemm_f8<1, false><<<320, 512, 0, stream>>>(sub8, M2_8, T1p8,
      1280, 1280, 5, 64, 0, 0, 0, nullptr, nullptr);

  // S[b] = T1'8 @ cyc8^T * 2^-16 + tbar x gsum -> bf16  [16,1024,2048]
  gemm_f8<0, true><<<512, 512, 0, stream>>>(T1p8, cyc8, S,
      1280, 2048, 8, 4, 1024l * 1280, 2048l * 1280, 1024l * 2048, tbar, gsum);

  softmax_wsum<<<dim3(16, 32), 256, 0, stream>>>(S, wsum);
  wcyc_kernel<<<dim3(16, 32), 320, 0, stream>>>(cyc8, wsum, tbuf);
  xv_kernel<<<dim3(5, 16), 256, 0, stream>>>(tbuf, Wv, xcat);
  mlp1_kernel<<<dim3(2, 16), 256, 0, stream>>>(xcat, W1, b1, h1);
  mlp23_kernel<<<16, 64, 0, stream>>>(h1, W2, b2, W3, b3, out);
}

// Round 12
// 515.713 us; speedup vs baseline: 1.3840x; 1.0189x over previous
//
#include <hip/hip_runtime.h>
#include <hip/hip_bf16.h>

#define DEV static __device__ __forceinline__

typedef __attribute__((ext_vector_type(16))) float f32x16;
typedef __attribute__((ext_vector_type(8)))  short bf16x8;

#if defined(__has_builtin)
#  if __has_builtin(__builtin_amdgcn_cvt_pk_fp8_f32) && __has_builtin(__builtin_amdgcn_cvt_f32_fp8)
#    define HW_FP8 1
#  endif
#endif

DEV ushort f2bf(float f){
  union { float f; unsigned u; } v; v.f = f;
  return (ushort)((v.u + 0x7FFFu + ((v.u >> 16) & 1u)) >> 16);
}
DEV float bf2f(ushort u){
  union { unsigned u; float f; } v; v.u = ((unsigned)u) << 16;
  return v.f;
}

DEV unsigned char f2e4m3_sw(float f){
  union { float f; unsigned u; } v; v.f = f;
  unsigned s = (v.u >> 24) & 0x80;
  float a = fabsf(f);
  if (a >= 448.f) return s | 0x7E;
  if (a < 0.0009765625f) return (unsigned char)s;
  if (a < 0.015625f) {
    int m = (int)rintf(a * 512.f);
    return (unsigned char)(s | (m >= 8 ? 8 : m));
  }
  unsigned ab = v.u & 0x7FFFFFFF;
  unsigned r = ab + 0x0007FFFF + ((ab >> 20) & 1);
  unsigned e = (r >> 23) - 127 + 7;
  unsigned m = (r >> 20) & 7;
  if (e > 15 || (e == 15 && m > 6)) return s | 0x7E;
  return (unsigned char)(s | (e << 3) | m);
}
DEV float e4m32f_sw(unsigned char c){
  unsigned e = (c >> 3) & 15, m = c & 7;
  float v;
  if (e) { union { unsigned u; float f; } w; w.u = ((e + 120u) << 23) | (m << 20); v = w.f; }
  else v = (float)m * 0.001953125f;
  return (c & 0x80) ? -v : v;
}

DEV unsigned pack4_fp8(float a, float b, float c, float d){
#ifdef HW_FP8
  int v = __builtin_amdgcn_cvt_pk_fp8_f32(a, b, 0, false);
  v = __builtin_amdgcn_cvt_pk_fp8_f32(c, d, v, true);
  return (unsigned)v;
#else
  return (unsigned)f2e4m3_sw(a) | ((unsigned)f2e4m3_sw(b) << 8)
       | ((unsigned)f2e4m3_sw(c) << 16) | ((unsigned)f2e4m3_sw(d) << 24);
#endif
}
DEV unsigned char enc_fp8(float a){
#ifdef HW_FP8
  return (unsigned char)(__builtin_amdgcn_cvt_pk_fp8_f32(a, a, 0, false) & 0xFF);
#else
  return f2e4m3_sw(a);
#endif
}
// byte-select must be an ICE for the builtin -> template parameter.
template<int SEL>
DEV float dec_fp8(unsigned u){
#ifdef HW_FP8
  return __builtin_amdgcn_cvt_f32_fp8((int)u, SEL);
#else
  return e4m32f_sw((u >> (SEL * 8)) & 0xFF);
#endif
}

// async global->LDS, 16B per lane; LDS dest is wave-uniform base + lane*16.
DEV void gload16(const void* g, void* l) {
  __builtin_amdgcn_global_load_lds(
      (const __attribute__((address_space(1))) unsigned*)g,
      (__attribute__((address_space(3))) unsigned*)l, 16, 0, 0);
}

// ---------------------------------------------------------------------------
// Elementwise f32 -> bf16 (Wq/Wk only).
// ---------------------------------------------------------------------------
__global__ __launch_bounds__(256)
void cvt_bf16(const float* __restrict__ src, ushort* __restrict__ dst, long n8)
{
  const long stride = (long)gridDim.x * 256;
  for (long i = (long)blockIdx.x * 256 + threadIdx.x; i < n8; i += stride) {
    const float4 a = *(const float4*)(src + i * 8);
    const float4 b = *(const float4*)(src + i * 8 + 4);
    union { ushort u[8]; uint4 v; } pk;
    pk.u[0] = f2bf(a.x); pk.u[1] = f2bf(a.y); pk.u[2] = f2bf(a.z); pk.u[3] = f2bf(a.w);
    pk.u[4] = f2bf(b.x); pk.u[5] = f2bf(b.y); pk.u[6] = f2bf(b.z); pk.u[7] = f2bf(b.w);
    *(uint4*)(dst + i * 8) = pk.v;
  }
}

// cyclase: f32 row -> fp8 row (x16) + exact f32 rowsum. Wave per row.
__global__ __launch_bounds__(256)
void cyccvt(const float* __restrict__ cyc, unsigned* __restrict__ cyc8w,
            float* __restrict__ gsum)
{
  const int lane = threadIdx.x & 63, wid = threadIdx.x >> 6;
  const long row = (long)blockIdx.x * 4 + wid;   // 32768 rows
  const float* src = cyc + row * 1280;
  unsigned* dst = cyc8w + row * 320;
  float s = 0.f;
  #pragma unroll
  for (int i = 0; i < 5; i++) {
    const int d = i * 256 + lane * 4;
    const float4 v = *(const float4*)(src + d);
    s += v.x + v.y + v.z + v.w;
    dst[d >> 2] = pack4_fp8(v.x * 16.f, v.y * 16.f, v.z * 16.f, v.w * 16.f);
  }
  #pragma unroll
  for (int o = 1; o < 64; o <<= 1) s += __shfl_xor(s, o);
  if (lane == 0) gsum[row] = s;
}

// substrate fused pass: f32 row read ONCE -> sub8 (fp8 x16) + exact tbar
// (rank-1 carrier, f32 dot with mcol).
__global__ __launch_bounds__(256)
void subprep(const float* __restrict__ sub, const float* __restrict__ mcol,
             unsigned* __restrict__ sub8w, float* __restrict__ tbar)
{
  __shared__ float mc[1280];
  for (int i = threadIdx.x; i < 1280; i += 256) mc[i] = mcol[i];
  __syncthreads();
  const int lane = threadIdx.x & 63, wid = threadIdx.x >> 6;
  const long row = (long)blockIdx.x * 4 + wid;   // 16384 rows
  const float4* sp = (const float4*)(sub + row * 1280);
  unsigned* dp = sub8w + row * 320;
  float d = 0.f;
  #pragma unroll
  for (int i = 0; i < 5; i++) {
    const int c = i * 64 + lane;
    const float4 v = sp[c];
    d += v.x * mc[c * 4] + v.y * mc[c * 4 + 1] + v.z * mc[c * 4 + 2] + v.w * mc[c * 4 + 3];
    dp[c] = pack4_fp8(v.x * 16.f, v.y * 16.f, v.z * 16.f, v.w * 16.f);
  }
  #pragma unroll
  for (int o = 1; o < 64; o <<= 1) d += __shfl_xor(d, o);
  if (lane == 0) tbar[row] = d;
}

// ---------------------------------------------------------------------------
// bf16 GEMM 8-phase (r6 structure, BM=128) — Mkq only (small).
// ---------------------------------------------------------------------------
__global__ __launch_bounds__(512, 4)
void gemm_mkq(const ushort* __restrict__ A, const ushort* __restrict__ B,
              ushort* __restrict__ C, int K, int N, int nbx, float scale)
{
  __shared__ __align__(16) ushort As[4][4][128][8];
  __shared__ __align__(16) ushort Bs[4][4][128][8];
  const int tid = threadIdx.x, lane = tid & 63, wid = tid >> 6;
  const int wr = wid >> 2, wc = wid & 3;
  const int bx = blockIdx.x % nbx, by = blockIdx.x / nbx;
  const int bm = by * 128, bn = bx * 128;

  f32x16 acc[2];
  #pragma unroll
  for (int i = 0; i < 2; i++)
    #pragma unroll
    for (int e = 0; e < 16; e++) acc[i][e] = 0.f;

  const int kbA = wid >> 1, rqA = wid & 1;
  const ushort* agp = A + (long)(bm + rqA * 64 + lane) * K + kbA * 8;
  const ushort* bgp = B + (long)(bn + rqA * 64 + lane) * K + kbA * 8;
  auto STAGE = [&](int g, int rg) {
    gload16(agp + g * 32, &As[rg][kbA][rqA * 64][0]);
    gload16(bgp + g * 32, &Bs[rg][kbA][rqA * 64][0]);
  };
  const int NG = K >> 5;
  STAGE(0, 0); STAGE(1, 1);
  asm volatile("s_waitcnt vmcnt(2)" ::: "memory");
  __builtin_amdgcn_s_barrier();
  const int lkh = lane >> 5, lr = lane & 31;
  auto GROUP = [&](int g, int rg, int rg2) {
    bf16x8 av[2][2], bv[2];
    #pragma unroll
    for (int kf = 0; kf < 2; kf++) {
      #pragma unroll
      for (int mi = 0; mi < 2; mi++)
        av[mi][kf] = *(const bf16x8*)&As[rg][kf * 2 + lkh][wr * 64 + mi * 32 + lr][0];
      bv[kf] = *(const bf16x8*)&Bs[rg][kf * 2 + lkh][wc * 32 + lr][0];
    }
    if (g + 2 < NG) STAGE(g + 2, rg2);
    __builtin_amdgcn_s_barrier();
    __builtin_amdgcn_s_setprio(1);
    #pragma unroll
    for (int mi = 0; mi < 2; mi++)
      #pragma unroll
      for (int kf = 0; kf < 2; kf++)
        acc[mi] = __builtin_amdgcn_mfma_f32_32x32x16_bf16(av[mi][kf], bv[kf], acc[mi], 0, 0, 0);
    __builtin_amdgcn_s_setprio(0);
    if (g + 2 < NG)      asm volatile("s_waitcnt vmcnt(2)" ::: "memory");
    else if (g + 1 < NG) asm volatile("s_waitcnt vmcnt(0)" ::: "memory");
    __builtin_amdgcn_s_barrier();
  };
  for (int g = 0; g < NG; g += 4) {
    GROUP(g, 0, 2); GROUP(g + 1, 1, 3); GROUP(g + 2, 2, 0); GROUP(g + 3, 3, 1);
  }
  #pragma unroll
  for (int mi = 0; mi < 2; mi++)
    #pragma unroll
    for (int rr = 0; rr < 16; rr++) {
      const int row = bm + wr * 64 + mi * 32 + (rr & 3) + 8 * (rr >> 2) + 4 * lkh;
      const int col = bn + wc * 32 + lr;
      C[(long)row * N + col] = f2bf(acc[mi][rr] * scale);
    }
}

// mcol[d] += partial col-mean.  Grid (5, 32).
__global__ __launch_bounds__(256)
void colmean(const ushort* __restrict__ Mkq, float* __restrict__ mcol)
{
  const int d = blockIdx.x * 256 + threadIdx.x;
  const int r0 = blockIdx.y * 40;
  float s = 0.f;
  for (int j = 0; j < 40; j++) s += bf2f(Mkq[(long)(r0 + j) * 1280 + d]);
  atomicAdd(&mcol[d], s * (1.f / 1280.f));
}

// M2_8[j][d] = e4m3((Mkq[j][d] - mcol[d]) * 2^19)
__global__ __launch_bounds__(320)
void m2cvt(const ushort* __restrict__ Mkq, const float* __restrict__ mcol,
           unsigned* __restrict__ M2w)
{
  const int j = blockIdx.x;
  const int d = threadIdx.x * 4;
  const ushort* mr = Mkq + (long)j * 1280 + d;
  const float* mc = mcol + d;
  M2w[j * 320 + threadIdx.x] = pack4_fp8(
      (bf2f(mr[0]) - mc[0]) * 524288.f, (bf2f(mr[1]) - mc[1]) * 524288.f,
      (bf2f(mr[2]) - mc[2]) * 524288.f, (bf2f(mr[3]) - mc[3]) * 524288.f);
}

// ---------------------------------------------------------------------------
// fp8 GEMM, RING=2 variant of the r10 8-phase kernel.  LDS 64 KB -> 2
// blocks/CU; per-group boundary is a vmcnt(0) drain of this wave's 4 loads,
// covered by the co-resident block (m114). BK=64 keeps work/barrier equal
// to r10 (avoids the r7 failure mode).
// MODE 0: C = bf16( acc*2^-16 + tbar[z*1024+row]*gsum[z*2048+col] )   (S)
// MODE 1: C = e4m3( acc * 2^-11 )                                     (T1')
// ---------------------------------------------------------------------------
template<int MODE, bool BY_FAST>
__global__ __launch_bounds__(512, 2)
void gemm_f8(const unsigned char* __restrict__ A, const unsigned char* __restrict__ B,
             void* __restrict__ Cv, int K, int N, int nbx, int nby,
             long sA, long sB, long sC,
             const float* __restrict__ tbar, const float* __restrict__ gsum)
{
  __shared__ __align__(16) unsigned char As[2][4][256][16];  // 32 KB
  __shared__ __align__(16) unsigned char Bs[2][4][256][16];  // 32 KB
  const int tid = threadIdx.x, lane = tid & 63, wid = tid >> 6;
  const int wr = wid >> 2, wc = wid & 3;

  const int nwg = gridDim.x;
  const int q = nwg >> 3, r = nwg & 7;
  const int xcd = blockIdx.x & 7, lid = blockIdx.x >> 3;
  const int id = (xcd < r ? xcd * (q + 1) : r * (q + 1) + (xcd - r) * q) + lid;
  const int per = nbx * nby;
  const int z = id / per, rem = id - z * per;
  const int bx = BY_FAST ? rem / nby : rem % nbx;
  const int by = BY_FAST ? rem % nby : rem / nbx;
  const int bm = by * 256, bn = bx * 256;
  const long Ab = (long)z * sA, Bb = (long)z * sB, Cb = (long)z * sC;

  f32x16 acc[4][2];
  #pragma unroll
  for (int i = 0; i < 4; i++)
    #pragma unroll
    for (int j = 0; j < 2; j++)
      #pragma unroll
      for (int e = 0; e < 16; e++) acc[i][j][e] = 0.f;

  const int c0 = wid * 2, c1 = wid * 2 + 1;
  const int kb0 = c0 >> 2, rq0 = c0 & 3, kb1 = c1 >> 2, rq1 = c1 & 3;
  const unsigned char* ag0 = A + Ab + (long)(bm + rq0 * 64 + lane) * K + kb0 * 16;
  const unsigned char* ag1 = A + Ab + (long)(bm + rq1 * 64 + lane) * K + kb1 * 16;
  const unsigned char* bg0 = B + Bb + (long)(bn + rq0 * 64 + lane) * K + kb0 * 16;
  const unsigned char* bg1 = B + Bb + (long)(bn + rq1 * 64 + lane) * K + kb1 * 16;
  auto STAGE_A = [&](int g, int s) {
    gload16(ag0 + g * 64, &As[s][kb0][rq0 * 64][0]);
    gload16(ag1 + g * 64, &As[s][kb1][rq1 * 64][0]);
  };
  auto STAGE_B = [&](int g, int s) {
    gload16(bg0 + g * 64, &Bs[s][kb0][rq0 * 64][0]);
    gload16(bg1 + g * 64, &Bs[s][kb1][rq1 * 64][0]);
  };

  const int NG = K >> 6;  // 64-K groups; even
  STAGE_A(0, 0); STAGE_B(0, 0);
  asm volatile("s_waitcnt vmcnt(0)" ::: "memory");
  __builtin_amdgcn_s_barrier();

  const int lkh = lane >> 5, lr = lane & 31;

  auto GROUP = [&](int g, int s) {
    const bool pre = (g + 1 < NG);
    long av[2][4], bv[2][4];
    #pragma unroll
    for (int kf = 0; kf < 4; kf++) {
      #pragma unroll
      for (int mi = 0; mi < 2; mi++)
        av[mi][kf] = *(const long*)&As[s][kf][wr * 128 + mi * 32 + lr][lkh * 8];
      #pragma unroll
      for (int ni = 0; ni < 2; ni++)
        bv[ni][kf] = *(const long*)&Bs[s][kf][wc * 64 + ni * 32 + lr][lkh * 8];
    }
    if (pre) STAGE_A(g + 1, s ^ 1);
    __builtin_amdgcn_s_barrier();
    __builtin_amdgcn_s_setprio(1);
    #pragma unroll
    for (int kf = 0; kf < 4; kf++)
      #pragma unroll
      for (int mi = 0; mi < 2; mi++)
        #pragma unroll
        for (int ni = 0; ni < 2; ni++)
          acc[mi][ni] = __builtin_amdgcn_mfma_f32_32x32x16_fp8_fp8(av[mi][kf], bv[ni][kf], acc[mi][ni], 0, 0, 0);
    __builtin_amdgcn_s_setprio(0);
    __builtin_amdgcn_s_barrier();
    #pragma unroll
    for (int kf = 0; kf < 4; kf++)
      #pragma unroll
      for (int mi = 0; mi < 2; mi++)
        av[mi][kf] = *(const long*)&As[s][kf][wr * 128 + (mi + 2) * 32 + lr][lkh * 8];
    if (pre) STAGE_B(g + 1, s ^ 1);
    __builtin_amdgcn_s_barrier();
    __builtin_amdgcn_s_setprio(1);
    #pragma unroll
    for (int kf = 0; kf < 4; kf++)
      #pragma unroll
      for (int mi = 0; mi < 2; mi++)
        #pragma unroll
        for (int ni = 0; ni < 2; ni++)
          acc[mi + 2][ni] = __builtin_amdgcn_mfma_f32_32x32x16_fp8_fp8(av[mi][kf], bv[ni][kf], acc[mi + 2][ni], 0, 0, 0);
    __builtin_amdgcn_s_setprio(0);
    if (pre) asm volatile("s_waitcnt vmcnt(0)" ::: "memory");
    __builtin_amdgcn_s_barrier();
  };

  for (int g = 0; g < NG; g += 2) { GROUP(g, 0); GROUP(g + 1, 1); }

  // C/D 32x32: col=lane&31, row=(reg&3)+8*(reg>>2)+4*(lane>>5)
  #pragma unroll
  for (int mi = 0; mi < 4; mi++)
    #pragma unroll
    for (int ni = 0; ni < 2; ni++)
      #pragma unroll
      for (int rr = 0; rr < 16; rr++) {
        const int row = bm + wr * 128 + mi * 32 + (rr & 3) + 8 * (rr >> 2) + 4 * lkh;
        const int col = bn + wc * 64 + ni * 32 + lr;
        if constexpr (MODE == 0) {
          const float v = acc[mi][ni][rr] * 0x1p-16f
                        + tbar[(long)z * 1024 + row] * gsum[(long)z * 2048 + col];
          ((ushort*)Cv)[Cb + (long)row * N + col] = f2bf(v);
        } else {
          ((unsigned char*)Cv)[Cb + (long)row * N + col] = enc_fp8(acc[mi][ni][rr] * 0x1p-11f);
        }
      }
}

// ---------------------------------------------------------------------------
// Softmax over c per (b,s) row of S (bf16); wsum[b,c] += softmax row.
// ---------------------------------------------------------------------------
__global__ __launch_bounds__(256)
void softmax_wsum(const ushort* __restrict__ S, float* __restrict__ wsum)
{
  const int b = blockIdx.x;
  const int s0 = blockIdx.y * 32;
  const int lane = threadIdx.x & 63;
  const int w = threadIdx.x >> 6;
  __shared__ float red[4][2048];
  const ushort* Sb = S + (((long)b * 1024) + s0 + w * 8) * 2048;

  float acc[32];
  #pragma unroll
  for (int i = 0; i < 32; i++) acc[i] = 0.f;
  for (int r = 0; r < 8; r++) {
    const ushort* row = Sb + (long)r * 2048;
    float v[32];
    #pragma unroll
    for (int i = 0; i < 4; i++) {
      uint4 u = *(const uint4*)(row + i * 512 + lane * 8);
      const ushort* up = (const ushort*)&u;
      #pragma unroll
      for (int j = 0; j < 8; j++) v[i * 8 + j] = bf2f(up[j]);
    }
    float m = v[0];
    #pragma unroll
    for (int i = 1; i < 32; i++) m = fmaxf(m, v[i]);
    #pragma unroll
    for (int o = 1; o < 64; o <<= 1) m = fmaxf(m, __shfl_xor(m, o));
    float ssum = 0.f;
    #pragma unroll
    for (int i = 0; i < 32; i++) { v[i] = __expf(v[i] - m); ssum += v[i]; }
    #pragma unroll
    for (int o = 1; o < 64; o <<= 1) ssum += __shfl_xor(ssum, o);
    const float inv = 1.f / ssum;
    #pragma unroll
    for (int i = 0; i < 32; i++) acc[i] += v[i] * inv;
  }
  #pragma unroll
  for (int i = 0; i < 4; i++)
    #pragma unroll
    for (int j = 0; j < 8; j++)
      red[w][i * 512 + lane * 8 + j] = acc[i * 8 + j];
  __syncthreads();
  float* wb = wsum + b * 2048;
  #pragma unroll
  for (int k = 0; k < 8; k++) {
    const int c = k * 256 + threadIdx.x;
    atomicAdd(&wb[c], red[0][c] + red[1][c] + red[2][c] + red[3][c]);
  }
}

// t[b,d] = sum_c wsum[b,c] * cyc8[b,c,d]/16
__global__ __launch_bounds__(320)
void wcyc_kernel(const unsigned char* __restrict__ cyc8, const float* __restrict__ wsum,
                 float* __restrict__ t)
{
  const int b = blockIdx.x;
  const int c0 = blockIdx.y * 64;
  const int d = threadIdx.x * 4;
  const unsigned char* cb = cyc8 + ((long)b * 2048 + c0) * 1280 + d;
  const float* wb = wsum + b * 2048 + c0;
  float4 a = {0.f, 0.f, 0.f, 0.f};
  for (int c = 0; c < 64; c++) {
    const unsigned u = *(const unsigned*)(cb + (long)c * 1280);
    const float w = wb[c];
    a.x += w * dec_fp8<0>(u); a.y += w * dec_fp8<1>(u);
    a.z += w * dec_fp8<2>(u); a.w += w * dec_fp8<3>(u);
  }
  atomicAdd(&t[b * 1280 + d + 0], a.x * 0.0625f);
  atomicAdd(&t[b * 1280 + d + 1], a.y * 0.0625f);
  atomicAdd(&t[b * 1280 + d + 2], a.z * 0.0625f);
  atomicAdd(&t[b * 1280 + d + 3], a.w * 0.0625f);
}

// xcat[b, 1280+d] = mean_s sub8[b,s,d]/16  (21 MB instead of 84 MB f32)
__global__ __launch_bounds__(320)
void submean8(const unsigned char* __restrict__ sub8, float* __restrict__ xcat)
{
  const int b = blockIdx.x;
  const int s0 = blockIdx.y * 256;
  const int d = threadIdx.x * 4;
  const unsigned char* sp = sub8 + ((long)b * 1024 + s0) * 1280 + d;
  float4 a = {0.f, 0.f, 0.f, 0.f};
  for (int s = 0; s < 256; s++) {
    const unsigned u = *(const unsigned*)(sp + (long)s * 1280);
    a.x += dec_fp8<0>(u); a.y += dec_fp8<1>(u);
    a.z += dec_fp8<2>(u); a.w += dec_fp8<3>(u);
  }
  const float k = 1.f / (16.f * 1024.f);
  atomicAdd(&xcat[b * 2560 + 1280 + d + 0], a.x * k);
  atomicAdd(&xcat[b * 2560 + 1280 + d + 1], a.y * k);
  atomicAdd(&xcat[b * 2560 + 1280 + d + 2], a.z * k);
  atomicAdd(&xcat[b * 2560 + 1280 + d + 3], a.w * k);
}

// xcat[b, dp] = (1/1024) * sum_d t[b,d] * Wv[d,dp]
__global__ __launch_bounds__(256)
void xv_kernel(const float* __restrict__ t, const float* __restrict__ Wv,
               float* __restrict__ xcat)
{
  const int b = blockIdx.y;
  const int dp = blockIdx.x * 256 + threadIdx.x;
  __shared__ float tl[1280];
  for (int i = threadIdx.x; i < 1280; i += 256) tl[i] = t[b * 1280 + i];
  __syncthreads();
  float a = 0.f;
  for (int d = 0; d < 1280; d++) a += tl[d] * Wv[(long)d * 1280 + dp];
  xcat[b * 2560 + dp] = a * (1.f / 1024.f);
}

// h1 = relu(xcat @ W1 + b1)
__global__ __launch_bounds__(256)
void mlp1_kernel(const float* __restrict__ xcat, const float* __restrict__ W1,
                 const float* __restrict__ b1, float* __restrict__ h1)
{
  const int b = blockIdx.y;
  const int j = blockIdx.x * 256 + threadIdx.x;
  __shared__ float xl[2560];
  for (int i = threadIdx.x; i < 2560; i += 256) xl[i] = xcat[b * 2560 + i];
  __syncthreads();
  float a = b1[j];
  for (int d = 0; d < 2560; d++) a += xl[d] * W1[(long)d * 512 + j];
  h1[b * 512 + j] = fmaxf(a, 0.f);
}

// h2 = relu(h1 @ W2 + b2); out = sigmoid(h2 @ W3 + b3)
__global__ __launch_bounds__(64)
void mlp23_kernel(const float* __restrict__ h1, const float* __restrict__ W2,
                  const float* __restrict__ b2, const float* __restrict__ W3,
                  const float* __restrict__ b3, float* __restrict__ out)
{
  const int b = blockIdx.x;
  const int j = threadIdx.x;
  __shared__ float hl[512];
  for (int i = j; i < 512; i += 64) hl[i] = h1[b * 512 + i];
  __syncthreads();
  float a = b2[j];
  for (int d = 0; d < 512; d++) a += hl[d] * W2[d * 64 + j];
  a = fmaxf(a, 0.f);
  float p = a * W3[j];
  #pragma unroll
  for (int o = 1; o < 64; o <<= 1) p += __shfl_xor(p, o);
  if (j == 0) out[b] = 1.f / (1.f + __expf(-(p + b3[0])));
}

extern "C" void kernel_launch(void* const* d_in, const int* in_sizes, int n_in,
                              void* d_out, int out_size, void* d_ws, size_t ws_size,
                              hipStream_t stream)
{
  const float* cyclase   = (const float*)d_in[0];
  const float* substrate = (const float*)d_in[1];
  const float* Wq = (const float*)d_in[4];
  const float* Wk = (const float*)d_in[5];
  const float* Wv = (const float*)d_in[6];
  const float* W1 = (const float*)d_in[7];
  const float* b1 = (const float*)d_in[8];
  const float* W2 = (const float*)d_in[9];
  const float* b2 = (const float*)d_in[10];
  const float* W3 = (const float*)d_in[11];
  const float* b3 = (const float*)d_in[12];
  float* out = (float*)d_out;
  (void)in_sizes; (void)n_in; (void)out_size; (void)ws_size;

  // Workspace (r10 layout):
  //  [0,42M)   cyc8                                     (cyccvt .. wcyc)
  //  [42M,..)  region2: Mkq/Wq16/Wk16/sub8 -> S bf16 overlays after all dead
  //  [~115M..) T1'8, M2_8, mcol, tbar, gsum, wsum, tbuf, xcat, h1
  char* ws = (char*)d_ws;
  unsigned char* cyc8 = (unsigned char*)ws;
  char* A2 = ws + 41943040;
  ushort* Mkq   = (ushort*)(A2 + 41943040);
  ushort* Wq16  = (ushort*)(A2 + 41943040 + 3276800);
  ushort* Wk16  = (ushort*)(A2 + 41943040 + 2 * 3276800);
  unsigned char* sub8 = (unsigned char*)(A2 + 41943040 + 3 * 3276800);
  ushort* S = (ushort*)A2;                       // overlays region2
  char* B2 = A2 + 41943040 + 3 * 3276800 + 20971520;
  unsigned char* T1p8 = (unsigned char*)B2;
  unsigned char* M2_8 = (unsigned char*)(B2 + 20971520);
  char* C2 = B2 + 20971520 + 1638400;
  float* mcol = (float*)C2;
  float* tbar = (float*)(C2 + 8192);
  float* gsum = (float*)(C2 + 8192 + 65536);
  float* wsum = (float*)(C2 + 8192 + 65536 + 131072);
  float* tbuf = (float*)(C2 + 8192 + 65536 + 2 * 131072);
  float* xcat = (float*)(C2 + 8192 + 65536 + 2 * 131072 + 81920);
  float* h1   = (float*)(C2 + 8192 + 65536 + 2 * 131072 + 81920 + 163840);

  hipMemsetAsync(mcol, 0, 1280 * 4, stream);
  hipMemsetAsync(wsum, 0, 16 * 2048 * 4, stream);
  hipMemsetAsync(tbuf, 0, 16 * 1280 * 4, stream);
  hipMemsetAsync(xcat, 0, 16 * 2560 * 4, stream);

  cvt_bf16<<<200, 256, 0, stream>>>(Wq, Wq16, 1280l * 1280 / 8);
  cvt_bf16<<<200, 256, 0, stream>>>(Wk, Wk16, 1280l * 1280 / 8);
  cyccvt<<<8192, 256, 0, stream>>>(cyclase, (unsigned*)cyc8, gsum);

  // Mkq = Wk @ Wq^T * (1/sqrt(1280))  [1280,1280] bf16
  gemm_mkq<<<100, 512, 0, stream>>>(Wk16, Wq16, Mkq, 1280, 1280, 10,
                                    0.02795084971874737f);
  colmean<<<dim3(5, 32), 256, 0, stream>>>(Mkq, mcol);
  m2cvt<<<1280, 320, 0, stream>>>(Mkq, mcol, (unsigned*)M2_8);

  // fused substrate pass (needs mcol): sub8 + exact tbar in one 84 MB read
  subprep<<<4096, 256, 0, stream>>>(substrate, mcol, (unsigned*)sub8, tbar);
  submean8<<<dim3(16, 4), 320, 0, stream>>>(sub8, xcat);

  // T1' = sub8 @ M2_8^T -> fp8 x4096   [16384,1280]   (320 blocks, 2/CU)
  gemm_f8<1, false><<<320, 512, 0, stream>>>(sub8, M2_8, T1p8,
      1280, 1280, 5, 64, 0, 0, 0, nullptr, nullptr);

  // S[b] = T1'8 @ cyc8^T * 2^-16 + tbar x gsum -> bf16  [16,1024,2048]
  gemm_f8<0, true><<<512, 512, 0, stream>>>(T1p8, cyc8, S,
      1280, 2048, 8, 4, 1024l * 1280, 2048l * 1280, 1024l * 2048, tbar, gsum);

  softmax_wsum<<<dim3(16, 32), 256, 0, stream>>>(S, wsum);
  wcyc_kernel<<<dim3(16, 32), 320, 0, stream>>>(cyc8, wsum, tbuf);
  xv_kernel<<<dim3(5, 16), 256, 0, stream>>>(tbuf, Wv, xcat);
  mlp1_kernel<<<dim3(2, 16), 256, 0, stream>>>(xcat, W1, b1, h1);
  mlp23_kernel<<<16, 64, 0, stream>>>(h1, W2, b2, W3, b3, out);
}